// Round 6
// baseline (238.903 us; speedup 1.0000x reference)
//
#include <hip/hip_runtime.h>
#include <hip/hip_cooperative_groups.h>
#include <math.h>

namespace cg = cooperative_groups;

#define EPSF 1e-8f
#define Tn 512
#define Dn 64
#define NELEM 65536

typedef _Float16 half_t;
typedef __attribute__((ext_vector_type(4))) _Float16 half4;

__device__ __forceinline__ float sigmoidf_(float x){ return 1.0f/(1.0f+__expf(-x)); }
__device__ __forceinline__ float softplusf_(float x){ return fmaxf(x,0.0f) + log1pf(__expf(-fabsf(x))); }

__device__ __forceinline__ float wrs(float v){
  #pragma unroll
  for (int off=1; off<64; off<<=1) v += __shfl_xor(v, off, 64);
  return v;
}
__device__ __forceinline__ float wrm(float v){
  #pragma unroll
  for (int off=1; off<64; off<<=1) v = fmaxf(v, __shfl_xor(v, off, 64));
  return v;
}

// ======================= fused cooperative path (NI=4, fp16 streams) =======================

// pnorm, one wave per row (i = wave 0..3). Writes s4[k*4+i] (fp32 LDS) and
// sTh k4-major fp16: half4 [(b*16+k4)*512 + r] via lane shuffles.
__device__ __forceinline__ void pnorm4h(float xg, int b, int r, int i, int lane,
                                        half_t* __restrict__ sTh_out, float* __restrict__ s4){
  float s = softplusf_(xg);
  float sum = wrs(s);
  float p = fmaxf(s/(sum+EPSF), EPSF);
  float s2 = wrs(p);
  float sq = sqrtf(p/(s2+EPSF));
  s4[lane*4 + i] = sq;
  int base = (lane*4)&63;
  float v0 = __shfl(sq, base,   64);
  float v1 = __shfl(sq, base+1, 64);
  float v2 = __shfl(sq, base+2, 64);
  float v3 = __shfl(sq, base+3, 64);
  if (lane < 16){
    half4 hv;
    hv.x=(half_t)v0; hv.y=(half_t)v1; hv.z=(half_t)v2; hv.w=(half_t)v3;
    ((half4*)sTh_out)[((size_t)b*16 + lane)*512 + r] = hv;
  }
}

// gate dot NI=4: 8 threads per output d, each dots 16 of 128, for 4 rows
__device__ __forceinline__ void gate_dot4(float (*comb)[128], float (*gred)[4],
                                          const float* __restrict__ Wfb, int tid, int lane){
  int dd = tid >> 3, k8 = tid & 7;
  const float4* wp = (const float4*)(Wfb + (size_t)dd*128 + k8*16);
  float4 w0 = wp[0], w1 = wp[1], w2 = wp[2], w3 = wp[3];
  float ga[4];
  #pragma unroll
  for (int i=0;i<4;i++){
    const float4* c4 = (const float4*)&comb[i][k8*16];
    float4 c0=c4[0], c1=c4[1], c2=c4[2], c3=c4[3];
    ga[i] = w0.x*c0.x + w0.y*c0.y + w0.z*c0.z + w0.w*c0.w
          + w1.x*c1.x + w1.y*c1.y + w1.z*c1.z + w1.w*c1.w
          + w2.x*c2.x + w2.y*c2.y + w2.z*c2.z + w2.w*c2.w
          + w3.x*c3.x + w3.y*c3.y + w3.z*c3.z + w3.w*c3.w;
  }
  #pragma unroll
  for (int off=1; off<8; off<<=1){
    #pragma unroll
    for (int i=0;i<4;i++) ga[i] += __shfl_xor(ga[i], off, 64);
  }
  if ((lane&7)==0){
    #pragma unroll
    for (int i=0;i<4;i++) gred[dd][i] = ga[i];
  }
}

#define XST 17   // LDS x-stash row stride in half4 units (16 data + 1 pad)

// 256 blocks x 512 threads (1 block/CU). Block owns rows {4bid..4bid+3}.
__global__ __launch_bounds__(512, 2) void k_fused(
    const float* __restrict__ basin_seq, const float* __restrict__ basin_coords,
    const float* __restrict__ W_temp, const float* __restrict__ b_temp,
    const float* __restrict__ res_scale,
    const float* __restrict__ W_fb, const float* __restrict__ b_fb,
    const float* __restrict__ Wc1, const float* __restrict__ bc1,
    const float* __restrict__ Wc2, const float* __restrict__ bc2,
    const float* __restrict__ Wu, const float* __restrict__ bu,
    const float* __restrict__ rsg, float* __restrict__ out, float* __restrict__ ws){

  __shared__ __align__(16) half4 xstash[512*XST]; // 69.6 KB fp16 x cache
  __shared__ __align__(16) float pvp[128*64];     // 32 KB PV partials
  __shared__ __align__(16) float P[512*4];        // 8 KB exp weights
  __shared__ __align__(16) float s4[64*4];        // own-row pnorm fp32
  __shared__ float redw[2][8][4];
  __shared__ __align__(16) float comb[4][128];
  __shared__ __align__(16) float gred[64][4];
  __shared__ float temps_l[8];
  __shared__ float rs_l[4];
  __shared__ float pooled_l[128];
  __shared__ float h1l[64];
  __shared__ float hbl[128];
  __shared__ float combb[128];
  __shared__ float nb_l[64];

  cg::grid_group grid = cg::this_grid();

  int tid = threadIdx.x, wav = tid>>6, lane = tid&63;
  int bid = blockIdx.x;
  int row0 = bid*4;
  int b = row0>>9;
  int rb = row0&511;
  int i_ = tid>>6, d_ = lane;   // (row, dim) mapping for tid<256

  // workspace: fp16 ping-pong buffers + pooled accumulator
  half_t* sThA = (half_t*)ws;                    // 65536 halves
  half_t* sThB = (half_t*)(ws + 32768);
  half_t* xhA  = (half_t*)(ws + 65536);
  half_t* xhB  = (half_t*)(ws + 98304);
  float*  pooled_g = ws + 131072;                // 128 floats

  float bs_r=0.f, xi_pre=0.f, st0_r=0.f, st1_r=0.f, st2_r=0.f, st3_r=0.f;

  auto ATTN = [&](const half_t* __restrict__ xh_in, const half_t* __restrict__ sTh_in,
                  int tidx, float rs) -> float {
    float invT = 1.0f/fmaxf(temps_l[tidx], 1e-6f);
    // stash x (fp16, 64 KB) into LDS, coalesced 8B copies
    {
      const half4* xg = (const half4*)(xh_in + (size_t)b*Tn*Dn);  // 8192 half4
      #pragma unroll
      for (int it=0; it<16; ++it){
        int g = it*512 + tid;
        int row = g>>4, c = g&15;
        xstash[row*XST + c] = xg[g];
      }
    }
    // dot: thread j = tid computes inner(i,j) for all 4 rows (fp16 k4-major stream)
    float a0=0.f, a1=0.f, a2=0.f, a3=0.f;
    {
      const half4* sT4 = (const half4*)sTh_in + (size_t)b*16*512;
      const float4* s4p = (const float4*)s4;
      #pragma unroll
      for (int c=0;c<16;++c){
        half4 kvh = sT4[(size_t)c*512 + tid];     // coalesced across lanes
        float kx=(float)kvh.x, ky=(float)kvh.y, kz=(float)kvh.z, kw=(float)kvh.w;
        float4 sa = s4p[4*c],   sb2 = s4p[4*c+1];
        float4 sc = s4p[4*c+2], sd  = s4p[4*c+3];
        a0=fmaf(kx,sa.x,a0);  a1=fmaf(kx,sa.y,a1);
        a2=fmaf(kx,sa.z,a2);  a3=fmaf(kx,sa.w,a3);
        a0=fmaf(ky,sb2.x,a0); a1=fmaf(ky,sb2.y,a1);
        a2=fmaf(ky,sb2.z,a2); a3=fmaf(ky,sb2.w,a3);
        a0=fmaf(kz,sc.x,a0);  a1=fmaf(kz,sc.y,a1);
        a2=fmaf(kz,sc.z,a2);  a3=fmaf(kz,sc.w,a3);
        a0=fmaf(kw,sd.x,a0);  a1=fmaf(kw,sd.y,a1);
        a2=fmaf(kw,sd.z,a2);  a3=fmaf(kw,sd.w,a3);
      }
    }
    // logits + softmax
    float lg[4];
    {
      float aa[4] = {a0,a1,a2,a3};
      #pragma unroll
      for (int i=0;i<4;i++){
        float cc = fminf(fmaxf(aa[i],-1.0f+1e-6f),1.0f-1e-6f);
        lg[i] = -2.0f*acosf(cc)*invT;
        float m = wrm(lg[i]);
        if (lane==0) redw[0][wav][i] = m;
      }
    }
    __syncthreads();
    {
      float e[4];
      #pragma unroll
      for (int i=0;i<4;i++){
        float mv = redw[0][0][i];
        #pragma unroll
        for (int w=1;w<8;w++) mv = fmaxf(mv, redw[0][w][i]);
        e[i] = __expf(lg[i]-mv);
      }
      *(float4*)&P[tid*4] = make_float4(e[0],e[1],e[2],e[3]);
      #pragma unroll
      for (int i=0;i<4;i++){
        float q = wrs(e[i]);
        if (lane==0) redw[1][wav][i] = q;
      }
    }
    __syncthreads();
    // PV from LDS stash: thread (jg,dq); rows j = jj*32 + jg (adjacent rows per wave)
    {
      int jg = tid>>4, dq = tid&15;
      float4 o0={0,0,0,0}, o1={0,0,0,0}, o2={0,0,0,0}, o3={0,0,0,0};
      #pragma unroll
      for (int jj=0; jj<16; ++jj){
        int j = jj*32 + jg;
        half4 xvh = xstash[j*XST + dq];
        float xx=(float)xvh.x, xy=(float)xvh.y, xz=(float)xvh.z, xw=(float)xvh.w;
        float4 pw = *(const float4*)&P[j*4];
        o0.x=fmaf(pw.x,xx,o0.x); o0.y=fmaf(pw.x,xy,o0.y);
        o0.z=fmaf(pw.x,xz,o0.z); o0.w=fmaf(pw.x,xw,o0.w);
        o1.x=fmaf(pw.y,xx,o1.x); o1.y=fmaf(pw.y,xy,o1.y);
        o1.z=fmaf(pw.y,xz,o1.z); o1.w=fmaf(pw.y,xw,o1.w);
        o2.x=fmaf(pw.z,xx,o2.x); o2.y=fmaf(pw.z,xy,o2.y);
        o2.z=fmaf(pw.z,xz,o2.z); o2.w=fmaf(pw.z,xw,o2.w);
        o3.x=fmaf(pw.w,xx,o3.x); o3.y=fmaf(pw.w,xy,o3.y);
        o3.z=fmaf(pw.w,xz,o3.z); o3.w=fmaf(pw.w,xw,o3.w);
      }
      *(float4*)&pvp[(jg*4+0)*64 + dq*4] = o0;
      *(float4*)&pvp[(jg*4+1)*64 + dq*4] = o1;
      *(float4*)&pvp[(jg*4+2)*64 + dq*4] = o2;
      *(float4*)&pvp[(jg*4+3)*64 + dq*4] = o3;
    }
    __syncthreads();
    float o = 0.f;
    if (tid < 256){
      float ss = 0.f;
      #pragma unroll
      for (int jg=0; jg<32; ++jg) ss += pvp[(jg*4+i_)*64+d_];
      float sv = 0.f;
      #pragma unroll
      for (int w=0;w<8;w++) sv += redw[1][w][i_];
      o = xi_pre + rs*(ss/sv - xi_pre);
    }
    return o;
  };

  auto GATE_WRITE = [&](float xv, float pv, const float* __restrict__ Wl,
                        const float* __restrict__ bl,
                        half_t* __restrict__ xh_out, half_t* __restrict__ sTh_out) -> float {
    if (tid < 256){ comb[i_][d_]=xv; comb[i_][64+d_]=pv; }
    __syncthreads();
    gate_dot4(comb, gred, Wl, tid, lane);
    __syncthreads();
    float xg = 0.f;
    if (tid < 256){
      float g = sigmoidf_(gred[d_][i_] + bl[d_]);
      xg = xv*g + pv*(1.0f-g);
      xh_out[(size_t)(row0+i_)*Dn + d_] = (half_t)xg;
      pnorm4h(xg, b, rb+i_, i_, lane, sTh_out, s4);
    }
    return xg;
  };

  // ---- Stage A: prologue
  if (tid < 4) rs_l[tid] = res_scale[tid];
  if (tid < 64){
    float cbv = basin_coords[tid];
    #pragma unroll
    for (int l=0;l<4;l++){
      float v = wrs(W_temp[l*Dn + tid]*cbv);
      if (tid==0) temps_l[l] = sigmoidf_(v + b_temp[l]) + 0.5f;
    }
  }
  if (bid==0 && tid<128) pooled_g[tid] = 0.f;
  if (tid < 256){
    bs_r = basin_seq[(size_t)(row0+i_)*Dn + d_];
    xi_pre = bs_r;
    xhA[(size_t)(row0+i_)*Dn + d_] = (half_t)bs_r;
    pnorm4h(bs_r, b, rb+i_, i_, lane, sThA, s4);
  }
  grid.sync();

  // ---- Pass 0
  { // L0
    float o = ATTN(xhA, sThA, 0, rs_l[0]);
    if (tid < 256){
      st0_r = o; xi_pre = o;
      xhB[(size_t)(row0+i_)*Dn + d_] = (half_t)o;
      pnorm4h(o, b, rb+i_, i_, lane, sThB, s4);
    }
    grid.sync();
  }
  { // L1
    float o = ATTN(xhB, sThB, 1, rs_l[1]);
    if (tid < 256){
      st1_r = o; xi_pre = o;
      xhA[(size_t)(row0+i_)*Dn + d_] = (half_t)o;
      pnorm4h(o, b, rb+i_, i_, lane, sThA, s4);
    }
    grid.sync();
  }
  { // L2
    float o = ATTN(xhA, sThA, 2, rs_l[2]);
    if (tid < 256){
      st2_r = o; xi_pre = o;
      xhB[(size_t)(row0+i_)*Dn + d_] = (half_t)o;
      pnorm4h(o, b, rb+i_, i_, lane, sThB, s4);
    }
    grid.sync();
  }
  { // L3: keep in regs; pooled via per-block pre-reduction + atomics
    float o = ATTN(xhB, sThB, 3, rs_l[3]);
    if (tid < 256){ st3_r = o; xi_pre = o; comb[i_][d_] = o; }
    __syncthreads();
    if (tid < 64)
      atomicAdd(&pooled_g[b*Dn + d_],
                (comb[0][d_]+comb[1][d_]+comb[2][d_]+comb[3][d_]) * (1.0f/Tn));
    grid.sync();
  }

  // ---- Stage F: basin update (redundant per block) + P1L0 gate
  {
    if (tid < 128) pooled_l[tid] = pooled_g[tid];
    __syncthreads();
    if (tid < 64){
      int bb = tid>>5, h = tid&31;
      float acc=0.f;
      #pragma unroll 8
      for (int d2=0; d2<64; d2++) acc += pooled_l[bb*64+d2]*Wc1[h*64+d2];
      h1l[tid] = tanhf(acc + bc1[h]);
    }
    __syncthreads();
    if (tid < 128){
      int bb = tid>>6, d = tid&63;
      float acc=0.f;
      #pragma unroll 8
      for (int h2=0; h2<32; h2++) acc += h1l[bb*32+h2]*Wc2[d*32+h2];
      hbl[tid] = tanhf(acc + bc2[d]);
    }
    __syncthreads();
    if (tid < 64){
      combb[tid] = basin_coords[tid];
      combb[64+tid] = 0.5f*(hbl[tid] + hbl[64+tid]);
    }
    __syncthreads();
    if (tid < 64){
      float acc=0.f;
      #pragma unroll 8
      for (int k=0;k<128;k++) acc += Wu[tid*128+k]*combb[k];
      float g = sigmoidf_(acc + bu[tid]);
      nb_l[tid] = combb[tid]*(1.0f-g) + combb[64+tid]*g;
    }
    __syncthreads();
    if (tid < 64){
      float nb = nb_l[tid];
      #pragma unroll
      for (int l=0;l<4;l++){
        float v = wrs(W_temp[l*Dn + tid]*nb);
        if (tid==0) temps_l[4+l] = sigmoidf_(v + b_temp[l]) + 0.5f;
      }
    }
    float xg = GATE_WRITE(st3_r, st0_r, W_fb, b_fb, xhA, sThA);
    if (tid < 256) xi_pre = xg;
    grid.sync();
  }

  // ---- Pass 1
  { // P1 L0 + gate l=1 (prev=st1)
    float o = ATTN(xhA, sThA, 4, rs_l[0]);
    float xg = GATE_WRITE(o, st1_r, W_fb + (size_t)1*Dn*2*Dn, b_fb + 1*Dn, xhB, sThB);
    if (tid < 256) xi_pre = xg;
    grid.sync();
  }
  { // P1 L1 + gate l=2 (prev=st2)
    float o = ATTN(xhB, sThB, 5, rs_l[1]);
    float xg = GATE_WRITE(o, st2_r, W_fb + (size_t)2*Dn*2*Dn, b_fb + 2*Dn, xhA, sThA);
    if (tid < 256) xi_pre = xg;
    grid.sync();
  }
  { // P1 L2 + gate l=3 (prev=st3)
    float o = ATTN(xhA, sThA, 6, rs_l[2]);
    float xg = GATE_WRITE(o, st3_r, W_fb + (size_t)3*Dn*2*Dn, b_fb + 3*Dn, xhB, sThB);
    if (tid < 256) xi_pre = xg;
    grid.sync();
  }
  { // P1 L3 + final residual
    float o = ATTN(xhB, sThB, 7, rs_l[3]);
    if (tid < 256){
      float c = 0.01f * rsg[0];
      out[(size_t)(row0+i_)*Dn + d_] = o + c*(o - bs_r);
    }
  }
}

// ======================= fallback path (round-2, known-PASS) =======================

__device__ __forceinline__ void pnorm_w(float xg, int row, int d, float* __restrict__ sr_out){
  float s = softplusf_(xg);
  float sum = wrs(s);
  float p = fmaxf(s/(sum+EPSF), EPSF);
  float s2 = wrs(p);
  sr_out[(size_t)row*Dn + d] = sqrtf(p/(s2+EPSF));
}

__global__ __launch_bounds__(256) void k_prologue(
    const float* __restrict__ basin_seq, float* __restrict__ sA,
    const float* __restrict__ W_temp, const float* __restrict__ b_temp,
    const float* __restrict__ cb0, float* __restrict__ temps){
  int tid = threadIdx.x, wid = tid>>6, lane = tid&63;
  if (blockIdx.x < 256){
    int row = blockIdx.x*4 + wid;
    pnorm_w(basin_seq[(size_t)row*Dn+lane], row, lane, sA);
  } else if (tid < 64){
    float cbv = cb0[tid];
    #pragma unroll
    for (int l=0;l<4;l++){
      float v = wrs(W_temp[l*Dn + tid]*cbv);
      if (tid==0) temps[l] = sigmoidf_(v + b_temp[l]) + 0.5f;
    }
  }
}

__device__ __forceinline__ void gate_dot2(float (*comb)[128], float* gred,
                                          const float* __restrict__ Wfb, int tid, int lane){
  int dd = tid >> 3, k8 = tid & 7;
  const float4* wp = (const float4*)(Wfb + (size_t)dd*128 + k8*16);
  float4 w0 = wp[0], w1 = wp[1], w2 = wp[2], w3 = wp[3];
  float ga[2];
  #pragma unroll
  for (int i=0;i<2;i++){
    float4 c0 = *(const float4*)&comb[i][k8*16];
    float4 c1 = *(const float4*)&comb[i][k8*16+4];
    float4 c2 = *(const float4*)&comb[i][k8*16+8];
    float4 c3 = *(const float4*)&comb[i][k8*16+12];
    ga[i] = w0.x*c0.x + w0.y*c0.y + w0.z*c0.z + w0.w*c0.w
          + w1.x*c1.x + w1.y*c1.y + w1.z*c1.z + w1.w*c1.w
          + w2.x*c2.x + w2.y*c2.y + w2.z*c2.z + w2.w*c2.w
          + w3.x*c3.x + w3.y*c3.y + w3.z*c3.z + w3.w*c3.w;
  }
  #pragma unroll
  for (int off=1; off<8; off<<=1){
    ga[0] += __shfl_xor(ga[0],off,64); ga[1] += __shfl_xor(ga[1],off,64);
  }
  if ((lane&7)==0){ gred[dd*3+0]=ga[0]; gred[dd*3+1]=ga[1]; }
}

template<int MODE>
__global__ __launch_bounds__(512) void k_attn(
    const float* __restrict__ xin, const float* __restrict__ sr,
    const float* __restrict__ temps, const float* __restrict__ res_scale, int l,
    float* __restrict__ xout, float* __restrict__ sr_out,
    const float* __restrict__ Wfb, const float* __restrict__ bfb,
    const float* __restrict__ prev,
    const float* __restrict__ basin_seq, const float* __restrict__ rsg){
  __shared__ __align__(16) float pvp[64*64];
  __shared__ __align__(8)  float P[512*2];
  __shared__ __align__(16) float s01[64*2];
  __shared__ float redw[2][8][2];
  __shared__ __align__(16) float comb[2][128];
  __shared__ float gred[64*3];

  int tid = threadIdx.x, wav = tid>>6, lane = tid&63;
  int row0 = blockIdx.x*2, b = row0>>9;
  int i_ = tid>>6, d_ = lane;

  float xi_pre = 0.f, prev_pre = 0.f;
  if (tid < 128){
    s01[d_*2 + i_] = sr[(size_t)(row0+i_)*Dn + d_];
    xi_pre = xin[(size_t)(row0+i_)*Dn + d_];
    if constexpr (MODE == 2) prev_pre = prev[(size_t)(row0+i_)*Dn + d_];
  }
  __syncthreads();

  float invT = 1.0f/fmaxf(temps[l], 1e-6f);

  float a0=0.f, a1=0.f, b0=0.f, b1=0.f;
  {
    const float4* rj4 = (const float4*)(sr + (size_t)b*Tn*Dn + (size_t)tid*Dn);
    const float4* sp  = (const float4*)s01;
    #pragma unroll 8
    for (int c=0;c<16;++c){
      float4 x4 = rj4[c];
      float4 sa = sp[2*c], sb = sp[2*c+1];
      a0 = fmaf(x4.x, sa.x, a0); a1 = fmaf(x4.x, sa.y, a1);
      b0 = fmaf(x4.y, sa.z, b0); b1 = fmaf(x4.y, sa.w, b1);
      a0 = fmaf(x4.z, sb.x, a0); a1 = fmaf(x4.z, sb.y, a1);
      b0 = fmaf(x4.w, sb.z, b0); b1 = fmaf(x4.w, sb.w, b1);
    }
    a0 += b0; a1 += b1;
  }
  {
    float c0 = fminf(fmaxf(a0,-1.0f+1e-6f),1.0f-1e-6f);
    float c1 = fminf(fmaxf(a1,-1.0f+1e-6f),1.0f-1e-6f);
    float l0 = -2.0f*acosf(c0)*invT;
    float l1 = -2.0f*acosf(c1)*invT;
    float m0=wrm(l0), m1=wrm(l1);
    if (lane==0){ redw[0][wav][0]=m0; redw[0][wav][1]=m1; }
    __syncthreads();
    float mv0=redw[0][0][0], mv1=redw[0][0][1];
    #pragma unroll
    for (int w=1;w<8;w++){ mv0=fmaxf(mv0,redw[0][w][0]); mv1=fmaxf(mv1,redw[0][w][1]); }
    float e0=__expf(l0-mv0), e1=__expf(l1-mv1);
    *(float2*)&P[tid*2] = make_float2(e0,e1);
    float q0=wrs(e0), q1=wrs(e1);
    if (lane==0){ redw[1][wav][0]=q0; redw[1][wav][1]=q1; }
  }
  __syncthreads();
  {
    int jg = tid>>4, dq = tid&15;
    const float4* x4p = (const float4*)(xin + (size_t)b*Tn*Dn);
    float4 o0={0,0,0,0}, o1={0,0,0,0};
    int jb = jg*16;
    #pragma unroll 8
    for (int jj=0; jj<16; ++jj){
      int j = jb + jj;
      float4 xv = x4p[(size_t)j*16 + dq];
      float2 pw = *(const float2*)&P[j*2];
      o0.x=fmaf(pw.x,xv.x,o0.x); o0.y=fmaf(pw.x,xv.y,o0.y);
      o0.z=fmaf(pw.x,xv.z,o0.z); o0.w=fmaf(pw.x,xv.w,o0.w);
      o1.x=fmaf(pw.y,xv.x,o1.x); o1.y=fmaf(pw.y,xv.y,o1.y);
      o1.z=fmaf(pw.y,xv.z,o1.z); o1.w=fmaf(pw.y,xv.w,o1.w);
    }
    *(float4*)&pvp[(jg*2+0)*64 + dq*4] = o0;
    *(float4*)&pvp[(jg*2+1)*64 + dq*4] = o1;
  }
  __syncthreads();
  float o = 0.f;
  if (tid < 128){
    float ss = 0.f;
    #pragma unroll
    for (int jg=0; jg<32; ++jg) ss += pvp[(jg*2+i_)*64+d_];
    float sv = 0.f;
    #pragma unroll
    for (int w=0;w<8;w++) sv += redw[1][w][i_];
    float attn = ss/sv;
    o = xi_pre + res_scale[l]*(attn - xi_pre);
  }
  if constexpr (MODE == 0){
    if (tid < 128){
      xout[(size_t)(row0+i_)*Dn + d_] = o;
      pnorm_w(o, row0+i_, d_, sr_out);
    }
  } else if constexpr (MODE == 1){
    if (tid < 128) xout[(size_t)(row0+i_)*Dn + d_] = o;
  } else if constexpr (MODE == 2){
    if (tid < 128){
      comb[i_][d_] = o;
      comb[i_][64+d_] = prev_pre;
    }
    __syncthreads();
    gate_dot2(comb, gred, Wfb, tid, lane);
    __syncthreads();
    if (tid < 128){
      float g = sigmoidf_(gred[d_*3+i_] + bfb[d_]);
      float xg = o*g + prev_pre*(1.0f-g);
      xout[(size_t)(row0+i_)*Dn + d_] = xg;
      pnorm_w(xg, row0+i_, d_, sr_out);
    }
  } else {
    if (tid < 128){
      float c = 0.01f * rsg[0];
      xout[(size_t)(row0+i_)*Dn + d_] = o + c*(o - basin_seq[(size_t)(row0+i_)*Dn + d_]);
    }
  }
}

__global__ __launch_bounds__(256) void k_basinprep(
    const float* __restrict__ st3, const float* __restrict__ st0,
    const float* __restrict__ W_fb, const float* __restrict__ b_fb,
    float* __restrict__ xA, float* __restrict__ sA,
    const float* __restrict__ Wc1, const float* __restrict__ bc1,
    const float* __restrict__ Wc2, const float* __restrict__ bc2,
    const float* __restrict__ Wu,  const float* __restrict__ bu,
    const float* __restrict__ cb_in, float* __restrict__ cb_out,
    const float* __restrict__ W_temp, const float* __restrict__ b_temp,
    float* __restrict__ temps){
  int tid = threadIdx.x, wid = tid>>6, lane = tid&63;
  __shared__ __align__(16) float comb4[4][128];
  __shared__ float partial[256];
  __shared__ float pooled[128];
  __shared__ float h1[64];
  __shared__ float hb[128];
  __shared__ float combb[128];
  if (blockIdx.x < 256){
    int row = blockIdx.x*4 + wid;
    float xv = st3[(size_t)row*Dn+lane];
    float pvv = st0[(size_t)row*Dn+lane];
    comb4[wid][lane] = xv; comb4[wid][64+lane] = pvv;
    __syncthreads();
    const float4* W  = (const float4*)(W_fb + (size_t)lane*128);
    const float4* c4 = (const float4*)comb4[wid];
    float g0=0.f,g1=0.f;
    #pragma unroll
    for (int k=0;k<32;k+=2){
      float4 w0=W[k],   c0=c4[k];
      float4 w1=W[k+1], c1=c4[k+1];
      g0 += w0.x*c0.x + w0.y*c0.y + w0.z*c0.z + w0.w*c0.w;
      g1 += w1.x*c1.x + w1.y*c1.y + w1.z*c1.z + w1.w*c1.w;
    }
    float g = sigmoidf_(g0+g1 + b_fb[lane]);
    float xg = xv*g + pvv*(1.0f-g);
    xA[(size_t)row*Dn+lane] = xg;
    pnorm_w(xg, row, lane, sA);
  } else {
    {
      int bb = tid>>7, rem = tid&127, d = rem>>1, h = rem&1;
      const float* xb = st3 + (size_t)bb*Tn*Dn + d;
      float acc0=0.f,acc1=0.f,acc2=0.f,acc3=0.f;
      int t0 = h*256;
      for (int t=0;t<256;t+=4){
        acc0 += xb[(size_t)(t0+t  )*Dn];
        acc1 += xb[(size_t)(t0+t+1)*Dn];
        acc2 += xb[(size_t)(t0+t+2)*Dn];
        acc3 += xb[(size_t)(t0+t+3)*Dn];
      }
      partial[tid] = acc0+acc1+acc2+acc3;
    }
    __syncthreads();
    if (tid < 128){
      int bb = tid>>6, d = tid&63;
      pooled[tid] = (partial[bb*128+d*2] + partial[bb*128+d*2+1]) * (1.0f/Tn);
    }
    __syncthreads();
    if (tid < 64){
      int bb = tid >> 5, h = tid & 31;
      float acc=0.f;
      #pragma unroll 8
      for (int d2=0; d2<64; d2++) acc += pooled[bb*64+d2]*Wc1[h*64+d2];
      h1[tid] = tanhf(acc + bc1[h]);
    }
    __syncthreads();
    if (tid < 128){
      int bb = tid >> 6, d = tid & 63;
      float acc=0.f;
      #pragma unroll 8
      for (int h2=0; h2<32; h2++) acc += h1[bb*32+h2]*Wc2[d*32+h2];
      hb[tid] = tanhf(acc + bc2[d]);
    }
    __syncthreads();
    if (tid < 64){
      float agg = 0.5f*(hb[tid] + hb[64+tid]);
      combb[tid] = cb_in[tid];
      combb[64+tid] = agg;
    }
    __syncthreads();
    if (tid < 64){
      float acc=0.f;
      #pragma unroll 8
      for (int k=0;k<128;k++) acc += Wu[tid*128+k]*combb[k];
      float g = sigmoidf_(acc + bu[tid]);
      float nb = combb[tid]*(1.0f-g) + combb[64+tid]*g;
      cb_out[tid] = nb;
      #pragma unroll
      for (int l=0;l<4;l++){
        float v = wrs(W_temp[l*Dn + tid]*nb);
        if (tid==0) temps[l] = sigmoidf_(v + b_temp[l]) + 0.5f;
      }
    }
  }
}

// ======================= launcher =======================

extern "C" void kernel_launch(void* const* d_in, const int* in_sizes, int n_in,
                              void* d_out, int out_size, void* d_ws, size_t ws_size,
                              hipStream_t stream) {
  const float* basin_seq    = (const float*)d_in[0];
  const float* basin_coords = (const float*)d_in[1];
  const float* W_temp       = (const float*)d_in[2];
  const float* b_temp       = (const float*)d_in[3];
  const float* res_scale    = (const float*)d_in[4];
  const float* W_fb         = (const float*)d_in[5];
  const float* b_fb         = (const float*)d_in[6];
  const float* Wc1          = (const float*)d_in[7];
  const float* bc1          = (const float*)d_in[8];
  const float* Wc2          = (const float*)d_in[9];
  const float* bc2          = (const float*)d_in[10];
  const float* Wu           = (const float*)d_in[11];
  const float* bu           = (const float*)d_in[12];
  const float* rsg          = (const float*)d_in[13];
  float* out = (float*)d_out;
  float* ws  = (float*)d_ws;

  // one-time residency check for the cooperative path (host-side queries only)
  static int coop_ok = -1;
  if (coop_ok < 0){
    int dev = 0, coop_attr = 0, ncu = 0, nb = 0;
    hipError_t e0 = hipGetDevice(&dev);
    hipError_t e1 = hipDeviceGetAttribute(&coop_attr, hipDeviceAttributeCooperativeLaunch, dev);
    hipError_t e2 = hipDeviceGetAttribute(&ncu, hipDeviceAttributeMultiprocessorCount, dev);
    hipError_t e3 = hipOccupancyMaxActiveBlocksPerMultiprocessor(&nb, (const void*)k_fused, 512, 0);
    coop_ok = (e0==hipSuccess && e1==hipSuccess && e2==hipSuccess && e3==hipSuccess &&
               coop_attr != 0 && (long long)nb * ncu >= 256) ? 1 : 0;
  }

  if (coop_ok == 1){
    void* args[] = {
      (void*)&basin_seq, (void*)&basin_coords, (void*)&W_temp, (void*)&b_temp,
      (void*)&res_scale, (void*)&W_fb, (void*)&b_fb,
      (void*)&Wc1, (void*)&bc1, (void*)&Wc2, (void*)&bc2,
      (void*)&Wu, (void*)&bu, (void*)&rsg, (void*)&out, (void*)&ws
    };
    hipLaunchCooperativeKernel((const void*)k_fused, dim3(256), dim3(512),
                               args, 0, stream);
    return;
  }

  // fallback: known-good 10-dispatch chain (round-2)
  const size_t N = NELEM;
  float* srA   = ws;
  float* srB   = ws + N;
  float* st0   = ws + 2*N;
  float* st1   = ws + 3*N;
  float* st2   = ws + 4*N;
  float* st3   = ws + 5*N;
  float* xA    = ws + 6*N;
  float* xB    = ws + 7*N;
  float* temps = ws + 8*N;
  float* cb    = ws + 8*N + 64;

  const int GA = 512;

  k_prologue<<<257,256,0,stream>>>(basin_seq, srA, W_temp, b_temp, basin_coords, temps);
  k_attn<0><<<GA,512,0,stream>>>(basin_seq, srA, temps, res_scale, 0,
                                 st0, srB, nullptr,nullptr,nullptr,nullptr,nullptr);
  k_attn<0><<<GA,512,0,stream>>>(st0, srB, temps, res_scale, 1,
                                 st1, srA, nullptr,nullptr,nullptr,nullptr,nullptr);
  k_attn<0><<<GA,512,0,stream>>>(st1, srA, temps, res_scale, 2,
                                 st2, srB, nullptr,nullptr,nullptr,nullptr,nullptr);
  k_attn<1><<<GA,512,0,stream>>>(st2, srB, temps, res_scale, 3,
                                 st3, nullptr, nullptr,nullptr,nullptr,nullptr,nullptr);
  k_basinprep<<<257,256,0,stream>>>(st3, st0, W_fb, b_fb, xA, srA,
                                    Wc1, bc1, Wc2, bc2, Wu, bu,
                                    basin_coords, cb, W_temp, b_temp, temps);
  k_attn<2><<<GA,512,0,stream>>>(xA, srA, temps, res_scale, 0,
                                 xB, srB,
                                 W_fb + (size_t)1*Dn*2*Dn, b_fb + 1*Dn, st1, nullptr,nullptr);
  k_attn<2><<<GA,512,0,stream>>>(xB, srB, temps, res_scale, 1,
                                 xA, srA,
                                 W_fb + (size_t)2*Dn*2*Dn, b_fb + 2*Dn, st2, nullptr,nullptr);
  k_attn<2><<<GA,512,0,stream>>>(xA, srA, temps, res_scale, 2,
                                 xB, srB,
                                 W_fb + (size_t)3*Dn*2*Dn, b_fb + 3*Dn, st3, nullptr,nullptr);
  k_attn<3><<<GA,512,0,stream>>>(xB, srB, temps, res_scale, 3,
                                 out, nullptr, nullptr,nullptr,nullptr, basin_seq, rsg);
}

// Round 7
// 237.737 us; speedup vs baseline: 1.0049x; 1.0049x over previous
//
#include <hip/hip_runtime.h>
#include <hip/hip_cooperative_groups.h>
#include <math.h>

namespace cg = cooperative_groups;

#define EPSF 1e-8f
#define Tn 512
#define Dn 64
#define NELEM 65536

typedef _Float16 half_t;
typedef __attribute__((ext_vector_type(4))) _Float16 half4;
typedef __attribute__((ext_vector_type(8))) _Float16 half8;

__device__ __forceinline__ float sigmoidf_(float x){ return 1.0f/(1.0f+__expf(-x)); }
__device__ __forceinline__ float softplusf_(float x){ return fmaxf(x,0.0f) + log1pf(__expf(-fabsf(x))); }

__device__ __forceinline__ float wrs(float v){
  #pragma unroll
  for (int off=1; off<64; off<<=1) v += __shfl_xor(v, off, 64);
  return v;
}
__device__ __forceinline__ float wrm(float v){
  #pragma unroll
  for (int off=1; off<64; off<<=1) v = fmaxf(v, __shfl_xor(v, off, 64));
  return v;
}

// ======================= NEW: NI=2 coop path, 512 blocks (2 blocks/CU) =======================
// pnorm for NI=2; writes s01[k*2+i] (fp32 LDS) and k8-major half8 stream:
// sTh[(b*8+k8)*512 + r] = halves of k=8*k8..8*k8+7 for row r.
__device__ __forceinline__ void pnorm2h(float xg, int b, int r, int i, int lane,
                                        half_t* __restrict__ sTh_out, float* __restrict__ s01){
  float s = softplusf_(xg);
  float sum = wrs(s);
  float p = fmaxf(s/(sum+EPSF), EPSF);
  float s2 = wrs(p);
  float sq = sqrtf(p/(s2+EPSF));
  s01[lane*2 + i] = sq;
  float v[8];
  #pragma unroll
  for (int m=0;m<8;m++) v[m] = __shfl(sq, (lane&7)*8 + m, 64);
  if (lane < 8){
    half8 hv;
    #pragma unroll
    for (int m=0;m<8;m++) hv[m] = (half_t)v[m];
    ((half8*)sTh_out)[((size_t)b*8 + lane)*512 + r] = hv;
  }
}

// gate dot (NI=2): 8 threads per output d, each dots 16 of 128 (proven round-2)
__device__ __forceinline__ void gate_dot2(float (*comb)[128], float* gred,
                                          const float* __restrict__ Wfb, int tid, int lane){
  int dd = tid >> 3, k8 = tid & 7;
  const float4* wp = (const float4*)(Wfb + (size_t)dd*128 + k8*16);
  float4 w0 = wp[0], w1 = wp[1], w2 = wp[2], w3 = wp[3];
  float ga[2];
  #pragma unroll
  for (int i=0;i<2;i++){
    float4 c0 = *(const float4*)&comb[i][k8*16];
    float4 c1 = *(const float4*)&comb[i][k8*16+4];
    float4 c2 = *(const float4*)&comb[i][k8*16+8];
    float4 c3 = *(const float4*)&comb[i][k8*16+12];
    ga[i] = w0.x*c0.x + w0.y*c0.y + w0.z*c0.z + w0.w*c0.w
          + w1.x*c1.x + w1.y*c1.y + w1.z*c1.z + w1.w*c1.w
          + w2.x*c2.x + w2.y*c2.y + w2.z*c2.z + w2.w*c2.w
          + w3.x*c3.x + w3.y*c3.y + w3.z*c3.z + w3.w*c3.w;
  }
  #pragma unroll
  for (int off=1; off<8; off<<=1){
    ga[0] += __shfl_xor(ga[0],off,64); ga[1] += __shfl_xor(ga[1],off,64);
  }
  if ((lane&7)==0){ gred[dd*3+0]=ga[0]; gred[dd*3+1]=ga[1]; }
}

// 512 blocks x 512 threads = 2 blocks/CU, 16 waves/CU. Block owns rows {2bid, 2bid+1}.
__global__ __launch_bounds__(512, 4) void k_fused2(
    const float* __restrict__ basin_seq, const float* __restrict__ basin_coords,
    const float* __restrict__ W_temp, const float* __restrict__ b_temp,
    const float* __restrict__ res_scale,
    const float* __restrict__ W_fb, const float* __restrict__ b_fb,
    const float* __restrict__ Wc1, const float* __restrict__ bc1,
    const float* __restrict__ Wc2, const float* __restrict__ bc2,
    const float* __restrict__ Wu, const float* __restrict__ bu,
    const float* __restrict__ rsg, float* __restrict__ out, float* __restrict__ ws){

  __shared__ __align__(16) float pvp[128*64];  // [(jg*2+i)][d], jg 0..63   32 KB
  __shared__ __align__(16) float P[512*2];     // [j][i]                     4 KB
  __shared__ __align__(16) float s01[128];     // [k][i]
  __shared__ float redw[2][8][2];
  __shared__ __align__(16) float comb[2][128];
  __shared__ float gred[192];
  __shared__ float temps_l[8];
  __shared__ float rs_l[4];
  __shared__ float pooled_l[128];
  __shared__ float h1l[64];
  __shared__ float hbl[128];
  __shared__ float combb[128];
  __shared__ float nb_l[64];

  cg::grid_group grid = cg::this_grid();

  int tid = threadIdx.x, wav = tid>>6, lane = tid&63;
  int bid = blockIdx.x;
  int row0 = bid*2;
  int b = row0>>9;
  int rb = row0&511;
  int i_ = tid>>6, d_ = lane;   // (row, dim) mapping for tid<128

  half_t* sThA = (half_t*)ws;                    // 65536 halves (k8-major, 2 batches)
  half_t* sThB = (half_t*)(ws + 32768);
  half_t* xhA  = (half_t*)(ws + 65536);
  half_t* xhB  = (half_t*)(ws + 98304);
  float*  pooled_g = ws + 131072;

  float bs_r=0.f, xi_pre=0.f, st0_r=0.f, st1_r=0.f, st2_r=0.f, st3_r=0.f;

  auto ATTN = [&](const half_t* __restrict__ xh_in, const half_t* __restrict__ sTh_in,
                  int tidx, float rs) -> float {
    float invT = 1.0f/fmaxf(temps_l[tidx], 1e-6f);
    // dot: thread j = tid computes inner(i0,j), inner(i1,j); 8 x 16B coalesced loads
    float a0=0.f, a1=0.f;
    {
      const half8* sT8 = (const half8*)sTh_in + (size_t)b*8*512;
      const float4* sp = (const float4*)s01;
      #pragma unroll
      for (int c8=0;c8<8;++c8){
        half8 kv = sT8[(size_t)c8*512 + tid];
        float kf[8];
        #pragma unroll
        for (int m=0;m<8;m++) kf[m] = (float)kv[m];
        #pragma unroll
        for (int q=0;q<4;q++){
          float4 sv = sp[c8*4+q];       // {s01[2k],s01[2k+1],s01[2k+2],s01[2k+3]}
          a0 = fmaf(kf[2*q],   sv.x, a0); a1 = fmaf(kf[2*q],   sv.y, a1);
          a0 = fmaf(kf[2*q+1], sv.z, a0); a1 = fmaf(kf[2*q+1], sv.w, a1);
        }
      }
    }
    // logits + softmax
    {
      float c0 = fminf(fmaxf(a0,-1.0f+1e-6f),1.0f-1e-6f);
      float c1 = fminf(fmaxf(a1,-1.0f+1e-6f),1.0f-1e-6f);
      float l0 = -2.0f*acosf(c0)*invT;
      float l1 = -2.0f*acosf(c1)*invT;
      float m0=wrm(l0), m1=wrm(l1);
      if (lane==0){ redw[0][wav][0]=m0; redw[0][wav][1]=m1; }
      __syncthreads();
      float mv0=redw[0][0][0], mv1=redw[0][0][1];
      #pragma unroll
      for (int w=1;w<8;w++){ mv0=fmaxf(mv0,redw[0][w][0]); mv1=fmaxf(mv1,redw[0][w][1]); }
      float e0=__expf(l0-mv0), e1=__expf(l1-mv1);
      *(float2*)&P[tid*2] = make_float2(e0,e1);
      float q0=wrs(e0), q1=wrs(e1);
      if (lane==0){ redw[1][wav][0]=q0; redw[1][wav][1]=q1; }
    }
    __syncthreads();
    // PV: thread (jg, dq8); 8 j's (stride 64), half8 along d (16B coalesced)
    {
      int jg = tid>>3, dq8 = tid&7;
      const half8* x8 = (const half8*)(xh_in + (size_t)b*Tn*Dn);
      float o0[8], o1[8];
      #pragma unroll
      for (int m=0;m<8;m++){ o0[m]=0.f; o1[m]=0.f; }
      #pragma unroll
      for (int jj=0; jj<8; ++jj){
        int j = jj*64 + jg;
        half8 xv = x8[(size_t)j*8 + dq8];
        float2 pw = *(const float2*)&P[j*2];
        #pragma unroll
        for (int m=0;m<8;m++){
          float xf = (float)xv[m];
          o0[m] = fmaf(pw.x, xf, o0[m]);
          o1[m] = fmaf(pw.y, xf, o1[m]);
        }
      }
      float* p0 = &pvp[(jg*2+0)*64 + dq8*8];
      float* p1 = &pvp[(jg*2+1)*64 + dq8*8];
      *(float4*)p0     = make_float4(o0[0],o0[1],o0[2],o0[3]);
      *(float4*)(p0+4) = make_float4(o0[4],o0[5],o0[6],o0[7]);
      *(float4*)p1     = make_float4(o1[0],o1[1],o1[2],o1[3]);
      *(float4*)(p1+4) = make_float4(o1[4],o1[5],o1[6],o1[7]);
    }
    __syncthreads();
    float o = 0.f;
    if (tid < 128){
      float ss = 0.f;
      #pragma unroll
      for (int g=0; g<64; ++g) ss += pvp[(g*2+i_)*64+d_];
      float sv = 0.f;
      #pragma unroll
      for (int w=0;w<8;w++) sv += redw[1][w][i_];
      o = xi_pre + rs*(ss/sv - xi_pre);
    }
    return o;
  };

  auto GATE_WRITE = [&](float xv, float pv, const float* __restrict__ Wl,
                        const float* __restrict__ bl,
                        half_t* __restrict__ xh_out, half_t* __restrict__ sTh_out) -> float {
    if (tid < 128){ comb[i_][d_]=xv; comb[i_][64+d_]=pv; }
    __syncthreads();
    gate_dot2(comb, gred, Wl, tid, lane);
    __syncthreads();
    float xg = 0.f;
    if (tid < 128){
      float g = sigmoidf_(gred[d_*3+i_] + bl[d_]);
      xg = xv*g + pv*(1.0f-g);
      xh_out[(size_t)(row0+i_)*Dn + d_] = (half_t)xg;
      pnorm2h(xg, b, rb+i_, i_, lane, sTh_out, s01);
    }
    return xg;
  };

  // ---- Stage A: prologue
  if (tid < 4) rs_l[tid] = res_scale[tid];
  if (tid < 64){
    float cbv = basin_coords[tid];
    #pragma unroll
    for (int l=0;l<4;l++){
      float v = wrs(W_temp[l*Dn + tid]*cbv);
      if (tid==0) temps_l[l] = sigmoidf_(v + b_temp[l]) + 0.5f;
    }
  }
  if (bid==0 && tid<128) pooled_g[tid] = 0.f;
  if (tid < 128){
    bs_r = basin_seq[(size_t)(row0+i_)*Dn + d_];
    xi_pre = bs_r;
    xhA[(size_t)(row0+i_)*Dn + d_] = (half_t)bs_r;
    pnorm2h(bs_r, b, rb+i_, i_, lane, sThA, s01);
  }
  grid.sync();

  // ---- Pass 0
  { // L0
    float o = ATTN(xhA, sThA, 0, rs_l[0]);
    if (tid < 128){
      st0_r = o; xi_pre = o;
      xhB[(size_t)(row0+i_)*Dn + d_] = (half_t)o;
      pnorm2h(o, b, rb+i_, i_, lane, sThB, s01);
    }
    grid.sync();
  }
  { // L1
    float o = ATTN(xhB, sThB, 1, rs_l[1]);
    if (tid < 128){
      st1_r = o; xi_pre = o;
      xhA[(size_t)(row0+i_)*Dn + d_] = (half_t)o;
      pnorm2h(o, b, rb+i_, i_, lane, sThA, s01);
    }
    grid.sync();
  }
  { // L2
    float o = ATTN(xhA, sThA, 2, rs_l[2]);
    if (tid < 128){
      st2_r = o; xi_pre = o;
      xhB[(size_t)(row0+i_)*Dn + d_] = (half_t)o;
      pnorm2h(o, b, rb+i_, i_, lane, sThB, s01);
    }
    grid.sync();
  }
  { // L3: keep in regs; pooled via per-block pre-reduction + atomics
    float o = ATTN(xhB, sThB, 3, rs_l[3]);
    if (tid < 128){ st3_r = o; xi_pre = o; comb[i_][d_] = o; }
    __syncthreads();
    if (tid < 64)
      atomicAdd(&pooled_g[b*Dn + d_], (comb[0][d_]+comb[1][d_]) * (1.0f/Tn));
    grid.sync();
  }

  // ---- Stage F: basin update (redundant per block) + P1L0 gate
  {
    if (tid < 128) pooled_l[tid] = pooled_g[tid];
    __syncthreads();
    if (tid < 64){
      int bb = tid>>5, h = tid&31;
      float acc=0.f;
      #pragma unroll 8
      for (int d2=0; d2<64; d2++) acc += pooled_l[bb*64+d2]*Wc1[h*64+d2];
      h1l[tid] = tanhf(acc + bc1[h]);
    }
    __syncthreads();
    if (tid < 128){
      int bb = tid>>6, d = tid&63;
      float acc=0.f;
      #pragma unroll 8
      for (int h2=0; h2<32; h2++) acc += h1l[bb*32+h2]*Wc2[d*32+h2];
      hbl[tid] = tanhf(acc + bc2[d]);
    }
    __syncthreads();
    if (tid < 64){
      combb[tid] = basin_coords[tid];
      combb[64+tid] = 0.5f*(hbl[tid] + hbl[64+tid]);
    }
    __syncthreads();
    if (tid < 64){
      float acc=0.f;
      #pragma unroll 8
      for (int k=0;k<128;k++) acc += Wu[tid*128+k]*combb[k];
      float g = sigmoidf_(acc + bu[tid]);
      nb_l[tid] = combb[tid]*(1.0f-g) + combb[64+tid]*g;
    }
    __syncthreads();
    if (tid < 64){
      float nb = nb_l[tid];
      #pragma unroll
      for (int l=0;l<4;l++){
        float v = wrs(W_temp[l*Dn + tid]*nb);
        if (tid==0) temps_l[4+l] = sigmoidf_(v + b_temp[l]) + 0.5f;
      }
    }
    float xg = GATE_WRITE(st3_r, st0_r, W_fb, b_fb, xhA, sThA);
    if (tid < 128) xi_pre = xg;
    grid.sync();
  }

  // ---- Pass 1
  { // P1 L0 + gate l=1 (prev=st1)
    float o = ATTN(xhA, sThA, 4, rs_l[0]);
    float xg = GATE_WRITE(o, st1_r, W_fb + (size_t)1*Dn*2*Dn, b_fb + 1*Dn, xhB, sThB);
    if (tid < 128) xi_pre = xg;
    grid.sync();
  }
  { // P1 L1 + gate l=2 (prev=st2)
    float o = ATTN(xhB, sThB, 5, rs_l[1]);
    float xg = GATE_WRITE(o, st2_r, W_fb + (size_t)2*Dn*2*Dn, b_fb + 2*Dn, xhA, sThA);
    if (tid < 128) xi_pre = xg;
    grid.sync();
  }
  { // P1 L2 + gate l=3 (prev=st3)
    float o = ATTN(xhA, sThA, 6, rs_l[2]);
    float xg = GATE_WRITE(o, st3_r, W_fb + (size_t)3*Dn*2*Dn, b_fb + 3*Dn, xhB, sThB);
    if (tid < 128) xi_pre = xg;
    grid.sync();
  }
  { // P1 L3 + final residual
    float o = ATTN(xhB, sThB, 7, rs_l[3]);
    if (tid < 128){
      float c = 0.01f * rsg[0];
      out[(size_t)(row0+i_)*Dn + d_] = o + c*(o - bs_r);
    }
  }
}

// ======================= fallback 1: NI=4 coop (round-6, known-PASS 239us) =======================

__device__ __forceinline__ void pnorm4h(float xg, int b, int r, int i, int lane,
                                        half_t* __restrict__ sTh_out, float* __restrict__ s4){
  float s = softplusf_(xg);
  float sum = wrs(s);
  float p = fmaxf(s/(sum+EPSF), EPSF);
  float s2 = wrs(p);
  float sq = sqrtf(p/(s2+EPSF));
  s4[lane*4 + i] = sq;
  int base = (lane*4)&63;
  float v0 = __shfl(sq, base,   64);
  float v1 = __shfl(sq, base+1, 64);
  float v2 = __shfl(sq, base+2, 64);
  float v3 = __shfl(sq, base+3, 64);
  if (lane < 16){
    half4 hv;
    hv.x=(half_t)v0; hv.y=(half_t)v1; hv.z=(half_t)v2; hv.w=(half_t)v3;
    ((half4*)sTh_out)[((size_t)b*16 + lane)*512 + r] = hv;
  }
}

__device__ __forceinline__ void gate_dot4(float (*comb)[128], float (*gred)[4],
                                          const float* __restrict__ Wfb, int tid, int lane){
  int dd = tid >> 3, k8 = tid & 7;
  const float4* wp = (const float4*)(Wfb + (size_t)dd*128 + k8*16);
  float4 w0 = wp[0], w1 = wp[1], w2 = wp[2], w3 = wp[3];
  float ga[4];
  #pragma unroll
  for (int i=0;i<4;i++){
    const float4* c4 = (const float4*)&comb[i][k8*16];
    float4 c0=c4[0], c1=c4[1], c2=c4[2], c3=c4[3];
    ga[i] = w0.x*c0.x + w0.y*c0.y + w0.z*c0.z + w0.w*c0.w
          + w1.x*c1.x + w1.y*c1.y + w1.z*c1.z + w1.w*c1.w
          + w2.x*c2.x + w2.y*c2.y + w2.z*c2.z + w2.w*c2.w
          + w3.x*c3.x + w3.y*c3.y + w3.z*c3.z + w3.w*c3.w;
  }
  #pragma unroll
  for (int off=1; off<8; off<<=1){
    #pragma unroll
    for (int i=0;i<4;i++) ga[i] += __shfl_xor(ga[i], off, 64);
  }
  if ((lane&7)==0){
    #pragma unroll
    for (int i=0;i<4;i++) gred[dd][i] = ga[i];
  }
}

#define XST 17

__global__ __launch_bounds__(512, 2) void k_fused4(
    const float* __restrict__ basin_seq, const float* __restrict__ basin_coords,
    const float* __restrict__ W_temp, const float* __restrict__ b_temp,
    const float* __restrict__ res_scale,
    const float* __restrict__ W_fb, const float* __restrict__ b_fb,
    const float* __restrict__ Wc1, const float* __restrict__ bc1,
    const float* __restrict__ Wc2, const float* __restrict__ bc2,
    const float* __restrict__ Wu, const float* __restrict__ bu,
    const float* __restrict__ rsg, float* __restrict__ out, float* __restrict__ ws){

  __shared__ __align__(16) half4 xstash[512*XST];
  __shared__ __align__(16) float pvp[128*64];
  __shared__ __align__(16) float P[512*4];
  __shared__ __align__(16) float s4[64*4];
  __shared__ float redw[2][8][4];
  __shared__ __align__(16) float comb[4][128];
  __shared__ __align__(16) float gred[64][4];
  __shared__ float temps_l[8];
  __shared__ float rs_l[4];
  __shared__ float pooled_l[128];
  __shared__ float h1l[64];
  __shared__ float hbl[128];
  __shared__ float combb[128];
  __shared__ float nb_l[64];

  cg::grid_group grid = cg::this_grid();

  int tid = threadIdx.x, wav = tid>>6, lane = tid&63;
  int bid = blockIdx.x;
  int row0 = bid*4;
  int b = row0>>9;
  int rb = row0&511;
  int i_ = tid>>6, d_ = lane;

  half_t* sThA = (half_t*)ws;
  half_t* sThB = (half_t*)(ws + 32768);
  half_t* xhA  = (half_t*)(ws + 65536);
  half_t* xhB  = (half_t*)(ws + 98304);
  float*  pooled_g = ws + 131072;

  float bs_r=0.f, xi_pre=0.f, st0_r=0.f, st1_r=0.f, st2_r=0.f, st3_r=0.f;

  auto ATTN = [&](const half_t* __restrict__ xh_in, const half_t* __restrict__ sTh_in,
                  int tidx, float rs) -> float {
    float invT = 1.0f/fmaxf(temps_l[tidx], 1e-6f);
    {
      const half4* xg = (const half4*)(xh_in + (size_t)b*Tn*Dn);
      #pragma unroll
      for (int it=0; it<16; ++it){
        int g = it*512 + tid;
        int row = g>>4, c = g&15;
        xstash[row*XST + c] = xg[g];
      }
    }
    float a0=0.f, a1=0.f, a2=0.f, a3=0.f;
    {
      const half4* sT4 = (const half4*)sTh_in + (size_t)b*16*512;
      const float4* s4p = (const float4*)s4;
      #pragma unroll
      for (int c=0;c<16;++c){
        half4 kvh = sT4[(size_t)c*512 + tid];
        float kx=(float)kvh.x, ky=(float)kvh.y, kz=(float)kvh.z, kw=(float)kvh.w;
        float4 sa = s4p[4*c],   sb2 = s4p[4*c+1];
        float4 sc = s4p[4*c+2], sd  = s4p[4*c+3];
        a0=fmaf(kx,sa.x,a0);  a1=fmaf(kx,sa.y,a1);
        a2=fmaf(kx,sa.z,a2);  a3=fmaf(kx,sa.w,a3);
        a0=fmaf(ky,sb2.x,a0); a1=fmaf(ky,sb2.y,a1);
        a2=fmaf(ky,sb2.z,a2); a3=fmaf(ky,sb2.w,a3);
        a0=fmaf(kz,sc.x,a0);  a1=fmaf(kz,sc.y,a1);
        a2=fmaf(kz,sc.z,a2);  a3=fmaf(kz,sc.w,a3);
        a0=fmaf(kw,sd.x,a0);  a1=fmaf(kw,sd.y,a1);
        a2=fmaf(kw,sd.z,a2);  a3=fmaf(kw,sd.w,a3);
      }
    }
    float lg[4];
    {
      float aa[4] = {a0,a1,a2,a3};
      #pragma unroll
      for (int i=0;i<4;i++){
        float cc = fminf(fmaxf(aa[i],-1.0f+1e-6f),1.0f-1e-6f);
        lg[i] = -2.0f*acosf(cc)*invT;
        float m = wrm(lg[i]);
        if (lane==0) redw[0][wav][i] = m;
      }
    }
    __syncthreads();
    {
      float e[4];
      #pragma unroll
      for (int i=0;i<4;i++){
        float mv = redw[0][0][i];
        #pragma unroll
        for (int w=1;w<8;w++) mv = fmaxf(mv, redw[0][w][i]);
        e[i] = __expf(lg[i]-mv);
      }
      *(float4*)&P[tid*4] = make_float4(e[0],e[1],e[2],e[3]);
      #pragma unroll
      for (int i=0;i<4;i++){
        float q = wrs(e[i]);
        if (lane==0) redw[1][wav][i] = q;
      }
    }
    __syncthreads();
    {
      int jg = tid>>4, dq = tid&15;
      float4 o0={0,0,0,0}, o1={0,0,0,0}, o2={0,0,0,0}, o3={0,0,0,0};
      #pragma unroll
      for (int jj=0; jj<16; ++jj){
        int j = jj*32 + jg;
        half4 xvh = xstash[j*XST + dq];
        float xx=(float)xvh.x, xy=(float)xvh.y, xz=(float)xvh.z, xw=(float)xvh.w;
        float4 pw = *(const float4*)&P[j*4];
        o0.x=fmaf(pw.x,xx,o0.x); o0.y=fmaf(pw.x,xy,o0.y);
        o0.z=fmaf(pw.x,xz,o0.z); o0.w=fmaf(pw.x,xw,o0.w);
        o1.x=fmaf(pw.y,xx,o1.x); o1.y=fmaf(pw.y,xy,o1.y);
        o1.z=fmaf(pw.y,xz,o1.z); o1.w=fmaf(pw.y,xw,o1.w);
        o2.x=fmaf(pw.z,xx,o2.x); o2.y=fmaf(pw.z,xy,o2.y);
        o2.z=fmaf(pw.z,xz,o2.z); o2.w=fmaf(pw.z,xw,o2.w);
        o3.x=fmaf(pw.w,xx,o3.x); o3.y=fmaf(pw.w,xy,o3.y);
        o3.z=fmaf(pw.w,xz,o3.z); o3.w=fmaf(pw.w,xw,o3.w);
      }
      *(float4*)&pvp[(jg*4+0)*64 + dq*4] = o0;
      *(float4*)&pvp[(jg*4+1)*64 + dq*4] = o1;
      *(float4*)&pvp[(jg*4+2)*64 + dq*4] = o2;
      *(float4*)&pvp[(jg*4+3)*64 + dq*4] = o3;
    }
    __syncthreads();
    float o = 0.f;
    if (tid < 256){
      float ss = 0.f;
      #pragma unroll
      for (int jg=0; jg<32; ++jg) ss += pvp[(jg*4+i_)*64+d_];
      float sv = 0.f;
      #pragma unroll
      for (int w=0;w<8;w++) sv += redw[1][w][i_];
      o = xi_pre + rs*(ss/sv - xi_pre);
    }
    return o;
  };

  auto GATE_WRITE = [&](float xv, float pv, const float* __restrict__ Wl,
                        const float* __restrict__ bl,
                        half_t* __restrict__ xh_out, half_t* __restrict__ sTh_out) -> float {
    if (tid < 256){ comb[i_][d_]=xv; comb[i_][64+d_]=pv; }
    __syncthreads();
    gate_dot4(comb, gred, Wl, tid, lane);
    __syncthreads();
    float xg = 0.f;
    if (tid < 256){
      float g = sigmoidf_(gred[d_][i_] + bl[d_]);
      xg = xv*g + pv*(1.0f-g);
      xh_out[(size_t)(row0+i_)*Dn + d_] = (half_t)xg;
      pnorm4h(xg, b, rb+i_, i_, lane, sTh_out, s4);
    }
    return xg;
  };

  if (tid < 4) rs_l[tid] = res_scale[tid];
  if (tid < 64){
    float cbv = basin_coords[tid];
    #pragma unroll
    for (int l=0;l<4;l++){
      float v = wrs(W_temp[l*Dn + tid]*cbv);
      if (tid==0) temps_l[l] = sigmoidf_(v + b_temp[l]) + 0.5f;
    }
  }
  if (bid==0 && tid<128) pooled_g[tid] = 0.f;
  if (tid < 256){
    bs_r = basin_seq[(size_t)(row0+i_)*Dn + d_];
    xi_pre = bs_r;
    xhA[(size_t)(row0+i_)*Dn + d_] = (half_t)bs_r;
    pnorm4h(bs_r, b, rb+i_, i_, lane, sThA, s4);
  }
  grid.sync();

  {
    float o = ATTN(xhA, sThA, 0, rs_l[0]);
    if (tid < 256){
      st0_r = o; xi_pre = o;
      xhB[(size_t)(row0+i_)*Dn + d_] = (half_t)o;
      pnorm4h(o, b, rb+i_, i_, lane, sThB, s4);
    }
    grid.sync();
  }
  {
    float o = ATTN(xhB, sThB, 1, rs_l[1]);
    if (tid < 256){
      st1_r = o; xi_pre = o;
      xhA[(size_t)(row0+i_)*Dn + d_] = (half_t)o;
      pnorm4h(o, b, rb+i_, i_, lane, sThA, s4);
    }
    grid.sync();
  }
  {
    float o = ATTN(xhA, sThA, 2, rs_l[2]);
    if (tid < 256){
      st2_r = o; xi_pre = o;
      xhB[(size_t)(row0+i_)*Dn + d_] = (half_t)o;
      pnorm4h(o, b, rb+i_, i_, lane, sThB, s4);
    }
    grid.sync();
  }
  {
    float o = ATTN(xhB, sThB, 3, rs_l[3]);
    if (tid < 256){ st3_r = o; xi_pre = o; comb[i_][d_] = o; }
    __syncthreads();
    if (tid < 64)
      atomicAdd(&pooled_g[b*Dn + d_],
                (comb[0][d_]+comb[1][d_]+comb[2][d_]+comb[3][d_]) * (1.0f/Tn));
    grid.sync();
  }

  {
    if (tid < 128) pooled_l[tid] = pooled_g[tid];
    __syncthreads();
    if (tid < 64){
      int bb = tid>>5, h = tid&31;
      float acc=0.f;
      #pragma unroll 8
      for (int d2=0; d2<64; d2++) acc += pooled_l[bb*64+d2]*Wc1[h*64+d2];
      h1l[tid] = tanhf(acc + bc1[h]);
    }
    __syncthreads();
    if (tid < 128){
      int bb = tid>>6, d = tid&63;
      float acc=0.f;
      #pragma unroll 8
      for (int h2=0; h2<32; h2++) acc += h1l[bb*32+h2]*Wc2[d*32+h2];
      hbl[tid] = tanhf(acc + bc2[d]);
    }
    __syncthreads();
    if (tid < 64){
      combb[tid] = basin_coords[tid];
      combb[64+tid] = 0.5f*(hbl[tid] + hbl[64+tid]);
    }
    __syncthreads();
    if (tid < 64){
      float acc=0.f;
      #pragma unroll 8
      for (int k=0;k<128;k++) acc += Wu[tid*128+k]*combb[k];
      float g = sigmoidf_(acc + bu[tid]);
      nb_l[tid] = combb[tid]*(1.0f-g) + combb[64+tid]*g;
    }
    __syncthreads();
    if (tid < 64){
      float nb = nb_l[tid];
      #pragma unroll
      for (int l=0;l<4;l++){
        float v = wrs(W_temp[l*Dn + tid]*nb);
        if (tid==0) temps_l[4+l] = sigmoidf_(v + b_temp[l]) + 0.5f;
      }
    }
    float xg = GATE_WRITE(st3_r, st0_r, W_fb, b_fb, xhA, sThA);
    if (tid < 256) xi_pre = xg;
    grid.sync();
  }

  {
    float o = ATTN(xhA, sThA, 4, rs_l[0]);
    float xg = GATE_WRITE(o, st1_r, W_fb + (size_t)1*Dn*2*Dn, b_fb + 1*Dn, xhB, sThB);
    if (tid < 256) xi_pre = xg;
    grid.sync();
  }
  {
    float o = ATTN(xhB, sThB, 5, rs_l[1]);
    float xg = GATE_WRITE(o, st2_r, W_fb + (size_t)2*Dn*2*Dn, b_fb + 2*Dn, xhA, sThA);
    if (tid < 256) xi_pre = xg;
    grid.sync();
  }
  {
    float o = ATTN(xhA, sThA, 6, rs_l[2]);
    float xg = GATE_WRITE(o, st3_r, W_fb + (size_t)3*Dn*2*Dn, b_fb + 3*Dn, xhB, sThB);
    if (tid < 256) xi_pre = xg;
    grid.sync();
  }
  {
    float o = ATTN(xhB, sThB, 7, rs_l[3]);
    if (tid < 256){
      float c = 0.01f * rsg[0];
      out[(size_t)(row0+i_)*Dn + d_] = o + c*(o - bs_r);
    }
  }
}

// ======================= fallback 2: round-2 chain (known-PASS) =======================

__device__ __forceinline__ void pnorm_w(float xg, int row, int d, float* __restrict__ sr_out){
  float s = softplusf_(xg);
  float sum = wrs(s);
  float p = fmaxf(s/(sum+EPSF), EPSF);
  float s2 = wrs(p);
  sr_out[(size_t)row*Dn + d] = sqrtf(p/(s2+EPSF));
}

__global__ __launch_bounds__(256) void k_prologue(
    const float* __restrict__ basin_seq, float* __restrict__ sA,
    const float* __restrict__ W_temp, const float* __restrict__ b_temp,
    const float* __restrict__ cb0, float* __restrict__ temps){
  int tid = threadIdx.x, wid = tid>>6, lane = tid&63;
  if (blockIdx.x < 256){
    int row = blockIdx.x*4 + wid;
    pnorm_w(basin_seq[(size_t)row*Dn+lane], row, lane, sA);
  } else if (tid < 64){
    float cbv = cb0[tid];
    #pragma unroll
    for (int l=0;l<4;l++){
      float v = wrs(W_temp[l*Dn + tid]*cbv);
      if (tid==0) temps[l] = sigmoidf_(v + b_temp[l]) + 0.5f;
    }
  }
}

template<int MODE>
__global__ __launch_bounds__(512) void k_attn(
    const float* __restrict__ xin, const float* __restrict__ sr,
    const float* __restrict__ temps, const float* __restrict__ res_scale, int l,
    float* __restrict__ xout, float* __restrict__ sr_out,
    const float* __restrict__ Wfb, const float* __restrict__ bfb,
    const float* __restrict__ prev,
    const float* __restrict__ basin_seq, const float* __restrict__ rsg){
  __shared__ __align__(16) float pvp[64*64];
  __shared__ __align__(8)  float P[512*2];
  __shared__ __align__(16) float s01[64*2];
  __shared__ float redw[2][8][2];
  __shared__ __align__(16) float comb[2][128];
  __shared__ float gred[64*3];

  int tid = threadIdx.x, wav = tid>>6, lane = tid&63;
  int row0 = blockIdx.x*2, b = row0>>9;
  int i_ = tid>>6, d_ = lane;

  float xi_pre = 0.f, prev_pre = 0.f;
  if (tid < 128){
    s01[d_*2 + i_] = sr[(size_t)(row0+i_)*Dn + d_];
    xi_pre = xin[(size_t)(row0+i_)*Dn + d_];
    if constexpr (MODE == 2) prev_pre = prev[(size_t)(row0+i_)*Dn + d_];
  }
  __syncthreads();

  float invT = 1.0f/fmaxf(temps[l], 1e-6f);

  float a0=0.f, a1=0.f, b0=0.f, b1=0.f;
  {
    const float4* rj4 = (const float4*)(sr + (size_t)b*Tn*Dn + (size_t)tid*Dn);
    const float4* sp  = (const float4*)s01;
    #pragma unroll 8
    for (int c=0;c<16;++c){
      float4 x4 = rj4[c];
      float4 sa = sp[2*c], sb = sp[2*c+1];
      a0 = fmaf(x4.x, sa.x, a0); a1 = fmaf(x4.x, sa.y, a1);
      b0 = fmaf(x4.y, sa.z, b0); b1 = fmaf(x4.y, sa.w, b1);
      a0 = fmaf(x4.z, sb.x, a0); a1 = fmaf(x4.z, sb.y, a1);
      b0 = fmaf(x4.w, sb.z, b0); b1 = fmaf(x4.w, sb.w, b1);
    }
    a0 += b0; a1 += b1;
  }
  {
    float c0 = fminf(fmaxf(a0,-1.0f+1e-6f),1.0f-1e-6f);
    float c1 = fminf(fmaxf(a1,-1.0f+1e-6f),1.0f-1e-6f);
    float l0 = -2.0f*acosf(c0)*invT;
    float l1 = -2.0f*acosf(c1)*invT;
    float m0=wrm(l0), m1=wrm(l1);
    if (lane==0){ redw[0][wav][0]=m0; redw[0][wav][1]=m1; }
    __syncthreads();
    float mv0=redw[0][0][0], mv1=redw[0][0][1];
    #pragma unroll
    for (int w=1;w<8;w++){ mv0=fmaxf(mv0,redw[0][w][0]); mv1=fmaxf(mv1,redw[0][w][1]); }
    float e0=__expf(l0-mv0), e1=__expf(l1-mv1);
    *(float2*)&P[tid*2] = make_float2(e0,e1);
    float q0=wrs(e0), q1=wrs(e1);
    if (lane==0){ redw[1][wav][0]=q0; redw[1][wav][1]=q1; }
  }
  __syncthreads();
  {
    int jg = tid>>4, dq = tid&15;
    const float4* x4p = (const float4*)(xin + (size_t)b*Tn*Dn);
    float4 o0={0,0,0,0}, o1={0,0,0,0};
    int jb = jg*16;
    #pragma unroll 8
    for (int jj=0; jj<16; ++jj){
      int j = jb + jj;
      float4 xv = x4p[(size_t)j*16 + dq];
      float2 pw = *(const float2*)&P[j*2];
      o0.x=fmaf(pw.x,xv.x,o0.x); o0.y=fmaf(pw.x,xv.y,o0.y);
      o0.z=fmaf(pw.x,xv.z,o0.z); o0.w=fmaf(pw.x,xv.w,o0.w);
      o1.x=fmaf(pw.y,xv.x,o1.x); o1.y=fmaf(pw.y,xv.y,o1.y);
      o1.z=fmaf(pw.y,xv.z,o1.z); o1.w=fmaf(pw.y,xv.w,o1.w);
    }
    *(float4*)&pvp[(jg*2+0)*64 + dq*4] = o0;
    *(float4*)&pvp[(jg*2+1)*64 + dq*4] = o1;
  }
  __syncthreads();
  float o = 0.f;
  if (tid < 128){
    float ss = 0.f;
    #pragma unroll
    for (int jg=0; jg<32; ++jg) ss += pvp[(jg*2+i_)*64+d_];
    float sv = 0.f;
    #pragma unroll
    for (int w=0;w<8;w++) sv += redw[1][w][i_];
    float attn = ss/sv;
    o = xi_pre + res_scale[l]*(attn - xi_pre);
  }
  if constexpr (MODE == 0){
    if (tid < 128){
      xout[(size_t)(row0+i_)*Dn + d_] = o;
      pnorm_w(o, row0+i_, d_, sr_out);
    }
  } else if constexpr (MODE == 1){
    if (tid < 128) xout[(size_t)(row0+i_)*Dn + d_] = o;
  } else if constexpr (MODE == 2){
    if (tid < 128){
      comb[i_][d_] = o;
      comb[i_][64+d_] = prev_pre;
    }
    __syncthreads();
    gate_dot2(comb, gred, Wfb, tid, lane);
    __syncthreads();
    if (tid < 128){
      float g = sigmoidf_(gred[d_*3+i_] + bfb[d_]);
      float xg = o*g + prev_pre*(1.0f-g);
      xout[(size_t)(row0+i_)*Dn + d_] = xg;
      pnorm_w(xg, row0+i_, d_, sr_out);
    }
  } else {
    if (tid < 128){
      float c = 0.01f * rsg[0];
      xout[(size_t)(row0+i_)*Dn + d_] = o + c*(o - basin_seq[(size_t)(row0+i_)*Dn + d_]);
    }
  }
}

__global__ __launch_bounds__(256) void k_basinprep(
    const float* __restrict__ st3, const float* __restrict__ st0,
    const float* __restrict__ W_fb, const float* __restrict__ b_fb,
    float* __restrict__ xA, float* __restrict__ sA,
    const float* __restrict__ Wc1, const float* __restrict__ bc1,
    const float* __restrict__ Wc2, const float* __restrict__ bc2,
    const float* __restrict__ Wu,  const float* __restrict__ bu,
    const float* __restrict__ cb_in, float* __restrict__ cb_out,
    const float* __restrict__ W_temp, const float* __restrict__ b_temp,
    float* __restrict__ temps){
  int tid = threadIdx.x, wid = tid>>6, lane = tid&63;
  __shared__ __align__(16) float comb4[4][128];
  __shared__ float partial[256];
  __shared__ float pooled[128];
  __shared__ float h1[64];
  __shared__ float hb[128];
  __shared__ float combb[128];
  if (blockIdx.x < 256){
    int row = blockIdx.x*4 + wid;
    float xv = st3[(size_t)row*Dn+lane];
    float pvv = st0[(size_t)row*Dn+lane];
    comb4[wid][lane] = xv; comb4[wid][64+lane] = pvv;
    __syncthreads();
    const float4* W  = (const float4*)(W_fb + (size_t)lane*128);
    const float4* c4 = (const float4*)comb4[wid];
    float g0=0.f,g1=0.f;
    #pragma unroll
    for (int k=0;k<32;k+=2){
      float4 w0=W[k],   c0=c4[k];
      float4 w1=W[k+1], c1=c4[k+1];
      g0 += w0.x*c0.x + w0.y*c0.y + w0.z*c0.z + w0.w*c0.w;
      g1 += w1.x*c1.x + w1.y*c1.y + w1.z*c1.z + w1.w*c1.w;
    }
    float g = sigmoidf_(g0+g1 + b_fb[lane]);
    float xg = xv*g + pvv*(1.0f-g);
    xA[(size_t)row*Dn+lane] = xg;
    pnorm_w(xg, row, lane, sA);
  } else {
    {
      int bb = tid>>7, rem = tid&127, d = rem>>1, h = rem&1;
      const float* xb = st3 + (size_t)bb*Tn*Dn + d;
      float acc0=0.f,acc1=0.f,acc2=0.f,acc3=0.f;
      int t0 = h*256;
      for (int t=0;t<256;t+=4){
        acc0 += xb[(size_t)(t0+t  )*Dn];
        acc1 += xb[(size_t)(t0+t+1)*Dn];
        acc2 += xb[(size_t)(t0+t+2)*Dn];
        acc3 += xb[(size_t)(t0+t+3)*Dn];
      }
      partial[tid] = acc0+acc1+acc2+acc3;
    }
    __syncthreads();
    if (tid < 128){
      int bb = tid>>6, d = tid&63;
      pooled[tid] = (partial[bb*128+d*2] + partial[bb*128+d*2+1]) * (1.0f/Tn);
    }
    __syncthreads();
    if (tid < 64){
      int bb = tid >> 5, h = tid & 31;
      float acc=0.f;
      #pragma unroll 8
      for (int d2=0; d2<64; d2++) acc += pooled[bb*64+d2]*Wc1[h*64+d2];
      h1[tid] = tanhf(acc + bc1[h]);
    }
    __syncthreads();
    if (tid < 128){
      int bb = tid >> 6, d = tid & 63;
      float acc=0.f;
      #pragma unroll 8
      for (int h2=0; h2<32; h2++) acc += h1[bb*32+h2]*Wc2[d*32+h2];
      hb[tid] = tanhf(acc + bc2[d]);
    }
    __syncthreads();
    if (tid < 64){
      float agg = 0.5f*(hb[tid] + hb[64+tid]);
      combb[tid] = cb_in[tid];
      combb[64+tid] = agg;
    }
    __syncthreads();
    if (tid < 64){
      float acc=0.f;
      #pragma unroll 8
      for (int k=0;k<128;k++) acc += Wu[tid*128+k]*combb[k];
      float g = sigmoidf_(acc + bu[tid]);
      float nb = combb[tid]*(1.0f-g) + combb[64+tid]*g;
      cb_out[tid] = nb;
      #pragma unroll
      for (int l=0;l<4;l++){
        float v = wrs(W_temp[l*Dn + tid]*nb);
        if (tid==0) temps[l] = sigmoidf_(v + b_temp[l]) + 0.5f;
      }
    }
  }
}

// ======================= launcher =======================

extern "C" void kernel_launch(void* const* d_in, const int* in_sizes, int n_in,
                              void* d_out, int out_size, void* d_ws, size_t ws_size,
                              hipStream_t stream) {
  const float* basin_seq    = (const float*)d_in[0];
  const float* basin_coords = (const float*)d_in[1];
  const float* W_temp       = (const float*)d_in[2];
  const float* b_temp       = (const float*)d_in[3];
  const float* res_scale    = (const float*)d_in[4];
  const float* W_fb         = (const float*)d_in[5];
  const float* b_fb         = (const float*)d_in[6];
  const float* Wc1          = (const float*)d_in[7];
  const float* bc1          = (const float*)d_in[8];
  const float* Wc2          = (const float*)d_in[9];
  const float* bc2          = (const float*)d_in[10];
  const float* Wu           = (const float*)d_in[11];
  const float* bu           = (const float*)d_in[12];
  const float* rsg          = (const float*)d_in[13];
  float* out = (float*)d_out;
  float* ws  = (float*)d_ws;

  // one-time residency checks (host-side queries only; proven capture-safe)
  static int mode = -1;
  if (mode < 0){
    int dev = 0, coop_attr = 0, ncu = 0, nb2 = 0, nb4 = 0;
    hipError_t e0 = hipGetDevice(&dev);
    hipError_t e1 = hipDeviceGetAttribute(&coop_attr, hipDeviceAttributeCooperativeLaunch, dev);
    hipError_t e2 = hipDeviceGetAttribute(&ncu, hipDeviceAttributeMultiprocessorCount, dev);
    hipError_t e3 = hipOccupancyMaxActiveBlocksPerMultiprocessor(&nb2, (const void*)k_fused2, 512, 0);
    hipError_t e4 = hipOccupancyMaxActiveBlocksPerMultiprocessor(&nb4, (const void*)k_fused4, 512, 0);
    bool ok = (e0==hipSuccess && e1==hipSuccess && e2==hipSuccess && coop_attr != 0);
    if (ok && e3==hipSuccess && (long long)nb2 * ncu >= 512) mode = 2;
    else if (ok && e4==hipSuccess && (long long)nb4 * ncu >= 256) mode = 1;
    else mode = 0;
  }

  if (mode >= 1){
    void* args[] = {
      (void*)&basin_seq, (void*)&basin_coords, (void*)&W_temp, (void*)&b_temp,
      (void*)&res_scale, (void*)&W_fb, (void*)&b_fb,
      (void*)&Wc1, (void*)&bc1, (void*)&Wc2, (void*)&bc2,
      (void*)&Wu, (void*)&bu, (void*)&rsg, (void*)&out, (void*)&ws
    };
    if (mode == 2)
      hipLaunchCooperativeKernel((const void*)k_fused2, dim3(512), dim3(512), args, 0, stream);
    else
      hipLaunchCooperativeKernel((const void*)k_fused4, dim3(256), dim3(512), args, 0, stream);
    return;
  }

  // last resort: known-good 10-dispatch chain (round-2)
  const size_t N = NELEM;
  float* srA   = ws;
  float* srB   = ws + N;
  float* st0   = ws + 2*N;
  float* st1   = ws + 3*N;
  float* st2   = ws + 4*N;
  float* st3   = ws + 5*N;
  float* xA    = ws + 6*N;
  float* xB    = ws + 7*N;
  float* temps = ws + 8*N;
  float* cb    = ws + 8*N + 64;

  const int GA = 512;

  k_prologue<<<257,256,0,stream>>>(basin_seq, srA, W_temp, b_temp, basin_coords, temps);
  k_attn<0><<<GA,512,0,stream>>>(basin_seq, srA, temps, res_scale, 0,
                                 st0, srB, nullptr,nullptr,nullptr,nullptr,nullptr);
  k_attn<0><<<GA,512,0,stream>>>(st0, srB, temps, res_scale, 1,
                                 st1, srA, nullptr,nullptr,nullptr,nullptr,nullptr);
  k_attn<0><<<GA,512,0,stream>>>(st1, srA, temps, res_scale, 2,
                                 st2, srB, nullptr,nullptr,nullptr,nullptr,nullptr);
  k_attn<1><<<GA,512,0,stream>>>(st2, srB, temps, res_scale, 3,
                                 st3, nullptr, nullptr,nullptr,nullptr,nullptr,nullptr);
  k_basinprep<<<257,256,0,stream>>>(st3, st0, W_fb, b_fb, xA, srA,
                                    Wc1, bc1, Wc2, bc2, Wu, bu,
                                    basin_coords, cb, W_temp, b_temp, temps);
  k_attn<2><<<GA,512,0,stream>>>(xA, srA, temps, res_scale, 0,
                                 xB, srB,
                                 W_fb + (size_t)1*Dn*2*Dn, b_fb + 1*Dn, st1, nullptr,nullptr);
  k_attn<2><<<GA,512,0,stream>>>(xB, srB, temps, res_scale, 1,
                                 xA, srA,
                                 W_fb + (size_t)2*Dn*2*Dn, b_fb + 2*Dn, st2, nullptr,nullptr);
  k_attn<2><<<GA,512,0,stream>>>(xA, srA, temps, res_scale, 2,
                                 xB, srB,
                                 W_fb + (size_t)3*Dn*2*Dn, b_fb + 3*Dn, st3, nullptr,nullptr);
  k_attn<3><<<GA,512,0,stream>>>(xB, srB, temps, res_scale, 3,
                                 out, nullptr, nullptr,nullptr,nullptr, basin_seq, rsg);
}

// Round 8
// 168.503 us; speedup vs baseline: 1.4178x; 1.4109x over previous
//
#include <hip/hip_runtime.h>
#include <math.h>

#define EPSF 1e-8f
#define Tn 512
#define Dn 64
#define NELEM 65536

typedef _Float16 half_t;
typedef __attribute__((ext_vector_type(8))) _Float16 half8;

__device__ __forceinline__ float sigmoidf_(float x){ return 1.0f/(1.0f+__expf(-x)); }
__device__ __forceinline__ float softplusf_(float x){ return fmaxf(x,0.0f) + log1pf(__expf(-fabsf(x))); }

__device__ __forceinline__ float wrs(float v){
  #pragma unroll
  for (int off=1; off<64; off<<=1) v += __shfl_xor(v, off, 64);
  return v;
}
__device__ __forceinline__ float wrm(float v){
  #pragma unroll
  for (int off=1; off<64; off<<=1) v = fmaxf(v, __shfl_xor(v, off, 64));
  return v;
}

// pnorm for one row (one full wave). Writes fp32 sr row (coalesced) and the
// fp16 k8-major transposed stream: sTh[(b*8+k8)*512 + r] = half8 of dims 8k8..8k8+7.
__device__ __forceinline__ void pnorm_g(float xg, int b, int r, int lane,
                                        float* __restrict__ sr_row, half_t* __restrict__ sTh){
  float s = softplusf_(xg);
  float sum = wrs(s);
  float p = fmaxf(s/(sum+EPSF), EPSF);
  float s2 = wrs(p);
  float sq = sqrtf(p/(s2+EPSF));
  sr_row[lane] = sq;
  float v[8];
  #pragma unroll
  for (int m=0;m<8;m++) v[m] = __shfl(sq, (lane&7)*8 + m, 64);
  if (lane < 8){
    half8 hv;
    #pragma unroll
    for (int m=0;m<8;m++) hv[m] = (half_t)v[m];
    ((half8*)sTh)[((size_t)b*8 + lane)*512 + r] = hv;
  }
}

// gate dot (NI=2): 8 threads per output d, each dots 16 of 128 (proven)
__device__ __forceinline__ void gate_dot2(float (*comb)[128], float* gred,
                                          const float* __restrict__ Wfb, int tid, int lane){
  int dd = tid >> 3, k8 = tid & 7;
  const float4* wp = (const float4*)(Wfb + (size_t)dd*128 + k8*16);
  float4 w0 = wp[0], w1 = wp[1], w2 = wp[2], w3 = wp[3];
  float ga[2];
  #pragma unroll
  for (int i=0;i<2;i++){
    float4 c0 = *(const float4*)&comb[i][k8*16];
    float4 c1 = *(const float4*)&comb[i][k8*16+4];
    float4 c2 = *(const float4*)&comb[i][k8*16+8];
    float4 c3 = *(const float4*)&comb[i][k8*16+12];
    ga[i] = w0.x*c0.x + w0.y*c0.y + w0.z*c0.z + w0.w*c0.w
          + w1.x*c1.x + w1.y*c1.y + w1.z*c1.z + w1.w*c1.w
          + w2.x*c2.x + w2.y*c2.y + w2.z*c2.z + w2.w*c2.w
          + w3.x*c3.x + w3.y*c3.y + w3.z*c3.z + w3.w*c3.w;
  }
  #pragma unroll
  for (int off=1; off<8; off<<=1){
    ga[0] += __shfl_xor(ga[0],off,64); ga[1] += __shfl_xor(ga[1],off,64);
  }
  if ((lane&7)==0){ gred[dd*3+0]=ga[0]; gred[dd*3+1]=ga[1]; }
}

// ---- prologue: pnorm(basin_seq)+fp16 copy (blocks 0..255); temps + pooled-zero (block 256)
__global__ __launch_bounds__(256) void k_prologue(
    const float* __restrict__ basin_seq, float* __restrict__ srA, half_t* __restrict__ sThA,
    half_t* __restrict__ xh0,
    const float* __restrict__ W_temp, const float* __restrict__ b_temp,
    const float* __restrict__ cb0, float* __restrict__ temps0, float* __restrict__ pooled_g){
  int tid = threadIdx.x, wid = tid>>6, lane = tid&63;
  if (blockIdx.x < 256){
    int row = blockIdx.x*4 + wid;
    float xv = basin_seq[(size_t)row*Dn + lane];
    xh0[(size_t)row*Dn + lane] = (half_t)xv;
    pnorm_g(xv, row>>9, row&511, lane, srA + (size_t)row*Dn, sThA);
  } else {
    if (tid < 64){
      float cbv = cb0[tid];
      #pragma unroll
      for (int l=0;l<4;l++){
        float v = wrs(W_temp[l*Dn + tid]*cbv);
        if (tid==0) temps0[l] = sigmoidf_(v + b_temp[l]) + 0.5f;
      }
    }
    if (tid < 128) pooled_g[tid] = 0.f;
  }
}

// ---- QFI attention chain kernel. NI=2 rows/block, 512 blocks x 512 threads.
// MODE 0: standard (write x fp32+fp16 + pnorm)
// MODE 1: L3 (write st3, pooled atomics, fused P1L0 gate(st3,st0), pnorm)
// MODE 2: P1L0 (basin-MLP -> temps, write temps_p1, attn, gate(o,st1), pnorm)
// MODE 3: P1 mid (attn, gate(o,prev), pnorm)
// MODE 4: final (out = o + 0.01*rsg*(o - basin_seq))
template<int MODE>
__global__ __launch_bounds__(512) void k_attn(
    const float* __restrict__ xin, const half_t* __restrict__ xh_in,
    const float* __restrict__ sr_in, const half_t* __restrict__ sTh_in,
    const float* __restrict__ temps_in, const float* __restrict__ res_scale, int l,
    float* __restrict__ xout, half_t* __restrict__ xh_out,
    float* __restrict__ sr_out, half_t* __restrict__ sTh_out,
    const float* __restrict__ Wfb, const float* __restrict__ bfb,
    const float* __restrict__ prev,
    float* __restrict__ st3out, float* __restrict__ pooled_g, float* __restrict__ temps_out,
    const float* __restrict__ basin_coords,
    const float* __restrict__ Wc1, const float* __restrict__ bc1,
    const float* __restrict__ Wc2, const float* __restrict__ bc2,
    const float* __restrict__ Wu, const float* __restrict__ bu,
    const float* __restrict__ W_temp, const float* __restrict__ b_temp,
    const float* __restrict__ basin_seq, const float* __restrict__ rsg){

  __shared__ __align__(16) float pvp[128*64];   // 32 KB PV partials [(jg*2+i)][d]
  __shared__ __align__(16) float P[512*2];      // 4 KB exp weights [j][i]
  __shared__ __align__(16) float s01[128];      // [k][i] own-row pnorm fp32
  __shared__ float redw[2][8][2];
  __shared__ __align__(16) float comb[2][128];
  __shared__ float gred[192];
  __shared__ float temps_l[4];
  __shared__ float pooled_l[128];
  __shared__ float h1l[64];
  __shared__ float hbl[128];
  __shared__ float combb[128];
  __shared__ float nb_l[64];

  int tid = threadIdx.x, wav = tid>>6, lane = tid&63;
  int row0 = blockIdx.x*2, b = row0>>9, rb = row0&511;
  int i_ = tid>>6, d_ = lane;   // epilogue mapping for tid<128

  // ---- MODE 2: redundant basin MLP from pooled_g -> temps_l (+ publish temps_p1)
  if constexpr (MODE == 2){
    if (tid < 128) pooled_l[tid] = pooled_g[tid];
    __syncthreads();
    if (tid < 64){
      int bb = tid>>5, h = tid&31;
      float acc=0.f;
      #pragma unroll 8
      for (int d2=0; d2<64; d2++) acc += pooled_l[bb*64+d2]*Wc1[h*64+d2];
      h1l[tid] = tanhf(acc + bc1[h]);
    }
    __syncthreads();
    if (tid < 128){
      int bb = tid>>6, d = tid&63;
      float acc=0.f;
      #pragma unroll 8
      for (int h2=0; h2<32; h2++) acc += h1l[bb*32+h2]*Wc2[d*32+h2];
      hbl[tid] = tanhf(acc + bc2[d]);
    }
    __syncthreads();
    if (tid < 64){
      combb[tid] = basin_coords[tid];
      combb[64+tid] = 0.5f*(hbl[tid] + hbl[64+tid]);
    }
    __syncthreads();
    if (tid < 64){
      float acc=0.f;
      #pragma unroll 8
      for (int k=0;k<128;k++) acc += Wu[tid*128+k]*combb[k];
      float g = sigmoidf_(acc + bu[tid]);
      nb_l[tid] = combb[tid]*(1.0f-g) + combb[64+tid]*g;
    }
    __syncthreads();
    if (tid < 64){
      float nb = nb_l[tid];
      #pragma unroll
      for (int l2=0;l2<4;l2++){
        float v = wrs(W_temp[l2*Dn + tid]*nb);
        if (tid==0) temps_l[l2] = sigmoidf_(v + b_temp[l2]) + 0.5f;
      }
    }
    __syncthreads();
    if (tid < 4) temps_out[tid] = temps_l[tid];
  }

  // ---- own-row init
  float xi_pre = 0.f, prev_pre = 0.f;
  if (tid < 128){
    s01[d_*2 + i_] = sr_in[(size_t)(row0+i_)*Dn + d_];
    xi_pre = xin[(size_t)(row0+i_)*Dn + d_];
    if constexpr (MODE == 1 || MODE == 2 || MODE == 3)
      prev_pre = prev[(size_t)(row0+i_)*Dn + d_];
  }
  __syncthreads();

  float invT;
  if constexpr (MODE == 2) invT = 1.0f/fmaxf(temps_l[0], 1e-6f);
  else                     invT = 1.0f/fmaxf(temps_in[l], 1e-6f);

  // ---- dot: thread j = tid computes inner(i0,j), inner(i1,j); 8 x 16B coalesced loads
  float a0=0.f, a1=0.f;
  {
    const half8* sT8 = (const half8*)sTh_in + (size_t)b*8*512;
    const float4* sp = (const float4*)s01;
    #pragma unroll
    for (int c8=0;c8<8;++c8){
      half8 kv = sT8[(size_t)c8*512 + tid];
      float kf[8];
      #pragma unroll
      for (int m=0;m<8;m++) kf[m] = (float)kv[m];
      #pragma unroll
      for (int q=0;q<4;q++){
        float4 sv = sp[c8*4+q];
        a0 = fmaf(kf[2*q],   sv.x, a0); a1 = fmaf(kf[2*q],   sv.y, a1);
        a0 = fmaf(kf[2*q+1], sv.z, a0); a1 = fmaf(kf[2*q+1], sv.w, a1);
      }
    }
  }
  // ---- logits + softmax
  {
    float c0 = fminf(fmaxf(a0,-1.0f+1e-6f),1.0f-1e-6f);
    float c1 = fminf(fmaxf(a1,-1.0f+1e-6f),1.0f-1e-6f);
    float l0 = -2.0f*acosf(c0)*invT;
    float l1 = -2.0f*acosf(c1)*invT;
    float m0=wrm(l0), m1=wrm(l1);
    if (lane==0){ redw[0][wav][0]=m0; redw[0][wav][1]=m1; }
    __syncthreads();
    float mv0=redw[0][0][0], mv1=redw[0][0][1];
    #pragma unroll
    for (int w=1;w<8;w++){ mv0=fmaxf(mv0,redw[0][w][0]); mv1=fmaxf(mv1,redw[0][w][1]); }
    float e0=__expf(l0-mv0), e1=__expf(l1-mv1);
    *(float2*)&P[tid*2] = make_float2(e0,e1);
    float q0=wrs(e0), q1=wrs(e1);
    if (lane==0){ redw[1][wav][0]=q0; redw[1][wav][1]=q1; }
  }
  __syncthreads();
  // ---- PV: thread (jg, dq8); 8 j's (stride 64), half8 along d (16B coalesced)
  {
    int jg = tid>>3, dq8 = tid&7;
    const half8* x8 = (const half8*)(xh_in + (size_t)b*Tn*Dn);
    float o0[8], o1[8];
    #pragma unroll
    for (int m=0;m<8;m++){ o0[m]=0.f; o1[m]=0.f; }
    #pragma unroll
    for (int jj=0; jj<8; ++jj){
      int j = jj*64 + jg;
      half8 xv = x8[(size_t)j*8 + dq8];
      float2 pw = *(const float2*)&P[j*2];
      #pragma unroll
      for (int m=0;m<8;m++){
        float xf = (float)xv[m];
        o0[m] = fmaf(pw.x, xf, o0[m]);
        o1[m] = fmaf(pw.y, xf, o1[m]);
      }
    }
    float* p0 = &pvp[(jg*2+0)*64 + dq8*8];
    float* p1 = &pvp[(jg*2+1)*64 + dq8*8];
    *(float4*)p0     = make_float4(o0[0],o0[1],o0[2],o0[3]);
    *(float4*)(p0+4) = make_float4(o0[4],o0[5],o0[6],o0[7]);
    *(float4*)p1     = make_float4(o1[0],o1[1],o1[2],o1[3]);
    *(float4*)(p1+4) = make_float4(o1[4],o1[5],o1[6],o1[7]);
  }
  __syncthreads();
  // ---- epilogue reduce
  float o = 0.f;
  if (tid < 128){
    float ss = 0.f;
    #pragma unroll
    for (int g=0; g<64; ++g) ss += pvp[(g*2+i_)*64+d_];
    float sv = 0.f;
    #pragma unroll
    for (int w=0;w<8;w++) sv += redw[1][w][i_];
    o = xi_pre + res_scale[l]*(ss/sv - xi_pre);
  }

  if constexpr (MODE == 0){
    if (tid < 128){
      xout[(size_t)(row0+i_)*Dn + d_] = o;
      xh_out[(size_t)(row0+i_)*Dn + d_] = (half_t)o;
      pnorm_g(o, b, rb+i_, lane, sr_out + (size_t)(row0+i_)*Dn, sTh_out);
    }
  } else if constexpr (MODE == 4){
    if (tid < 128){
      float c = 0.01f * rsg[0];
      xout[(size_t)(row0+i_)*Dn + d_] = o + c*(o - basin_seq[(size_t)(row0+i_)*Dn + d_]);
    }
  } else {
    // MODE 1/2/3: fused gate with prev; MODE 1 also writes st3 + pooled atomics
    if (tid < 128){
      if constexpr (MODE == 1) st3out[(size_t)(row0+i_)*Dn + d_] = o;
      comb[i_][d_] = o;
      comb[i_][64+d_] = prev_pre;
    }
    __syncthreads();
    if constexpr (MODE == 1){
      if (tid < 64)
        atomicAdd(&pooled_g[b*Dn + tid], (comb[0][tid]+comb[1][tid]) * (1.0f/Tn));
    }
    gate_dot2(comb, gred, Wfb, tid, lane);
    __syncthreads();
    if (tid < 128){
      float g = sigmoidf_(gred[d_*3+i_] + bfb[d_]);
      float xg = o*g + prev_pre*(1.0f-g);
      xout[(size_t)(row0+i_)*Dn + d_] = xg;
      xh_out[(size_t)(row0+i_)*Dn + d_] = (half_t)xg;
      pnorm_g(xg, b, rb+i_, lane, sr_out + (size_t)(row0+i_)*Dn, sTh_out);
    }
  }
}

extern "C" void kernel_launch(void* const* d_in, const int* in_sizes, int n_in,
                              void* d_out, int out_size, void* d_ws, size_t ws_size,
                              hipStream_t stream) {
  const float* basin_seq    = (const float*)d_in[0];
  const float* basin_coords = (const float*)d_in[1];
  const float* W_temp       = (const float*)d_in[2];
  const float* b_temp       = (const float*)d_in[3];
  const float* res_scale    = (const float*)d_in[4];
  const float* W_fb         = (const float*)d_in[5];
  const float* b_fb         = (const float*)d_in[6];
  const float* Wc1          = (const float*)d_in[7];
  const float* bc1          = (const float*)d_in[8];
  const float* Wc2          = (const float*)d_in[9];
  const float* bc2          = (const float*)d_in[10];
  const float* Wu           = (const float*)d_in[11];
  const float* bu           = (const float*)d_in[12];
  const float* rsg          = (const float*)d_in[13];
  float* out = (float*)d_out;
  float* ws  = (float*)d_ws;

  const size_t N = NELEM; // 65536
  float* srA      = ws;
  float* srB      = ws + N;
  float* st0      = ws + 2*N;
  float* st1      = ws + 3*N;
  float* st2      = ws + 4*N;
  float* st3      = ws + 5*N;
  float* xA       = ws + 6*N;
  float* xB       = ws + 7*N;
  float* pooled   = ws + 8*N;          // 128
  float* temps0   = ws + 8*N + 128;    // 4
  float* temps_p1 = ws + 8*N + 136;    // 4
  half_t* hbase = (half_t*)(ws + 8*N + 256);
  half_t* xh0  = hbase;                //  65536 halves each
  half_t* xhA  = hbase + 1*(size_t)N;
  half_t* xhB  = hbase + 2*(size_t)N;
  half_t* sThA = hbase + 3*(size_t)N;
  half_t* sThB = hbase + 4*(size_t)N;

  const int GA = 512;
  const size_t WFB = (size_t)Dn*2*Dn;  // 8192

  // 1. prologue
  k_prologue<<<257,256,0,stream>>>(basin_seq, srA, sThA, xh0,
                                   W_temp, b_temp, basin_coords, temps0, pooled);
  // 2-4. pass-0 L0..L2
  k_attn<0><<<GA,512,0,stream>>>(basin_seq, xh0, srA, sThA, temps0, res_scale, 0,
      st0, xhA, srB, sThB, nullptr,nullptr,nullptr, nullptr,nullptr,nullptr,
      nullptr,nullptr,nullptr,nullptr,nullptr,nullptr,nullptr,nullptr,nullptr,nullptr,nullptr);
  k_attn<0><<<GA,512,0,stream>>>(st0, xhA, srB, sThB, temps0, res_scale, 1,
      st1, xhB, srA, sThA, nullptr,nullptr,nullptr, nullptr,nullptr,nullptr,
      nullptr,nullptr,nullptr,nullptr,nullptr,nullptr,nullptr,nullptr,nullptr,nullptr,nullptr);
  k_attn<0><<<GA,512,0,stream>>>(st1, xhB, srA, sThA, temps0, res_scale, 2,
      st2, xhA, srB, sThB, nullptr,nullptr,nullptr, nullptr,nullptr,nullptr,
      nullptr,nullptr,nullptr,nullptr,nullptr,nullptr,nullptr,nullptr,nullptr,nullptr,nullptr);
  // 5. pass-0 L3 + pooled atomics + fused P1L0 gate(st3, st0)
  k_attn<1><<<GA,512,0,stream>>>(st2, xhA, srB, sThB, temps0, res_scale, 3,
      xA, xhB, srA, sThA, W_fb, b_fb, st0, st3, pooled, nullptr,
      nullptr,nullptr,nullptr,nullptr,nullptr,nullptr,nullptr,nullptr,nullptr,nullptr,nullptr);
  // 6. P1 L0: basin MLP + attn + gate(o, st1)
  k_attn<2><<<GA,512,0,stream>>>(xA, xhB, srA, sThA, nullptr, res_scale, 0,
      xB, xhA, srB, sThB, W_fb + 1*WFB, b_fb + 1*Dn, st1, nullptr, pooled, temps_p1,
      basin_coords, Wc1, bc1, Wc2, bc2, Wu, bu, W_temp, b_temp, nullptr,nullptr);
  // 7. P1 L1 + gate(o, st2)
  k_attn<3><<<GA,512,0,stream>>>(xB, xhA, srB, sThB, temps_p1, res_scale, 1,
      xA, xhB, srA, sThA, W_fb + 2*WFB, b_fb + 2*Dn, st2, nullptr,nullptr,nullptr,
      nullptr,nullptr,nullptr,nullptr,nullptr,nullptr,nullptr,nullptr,nullptr,nullptr,nullptr);
  // 8. P1 L2 + gate(o, st3)
  k_attn<3><<<GA,512,0,stream>>>(xA, xhB, srA, sThA, temps_p1, res_scale, 2,
      xB, xhA, srB, sThB, W_fb + 3*WFB, b_fb + 3*Dn, st3, nullptr,nullptr,nullptr,
      nullptr,nullptr,nullptr,nullptr,nullptr,nullptr,nullptr,nullptr,nullptr,nullptr,nullptr);
  // 9. P1 L3 + final residual
  k_attn<4><<<GA,512,0,stream>>>(xB, xhA, srB, sThB, temps_p1, res_scale, 3,
      out, nullptr, nullptr, nullptr, nullptr,nullptr,nullptr, nullptr,nullptr,nullptr,
      nullptr,nullptr,nullptr,nullptr,nullptr,nullptr,nullptr,nullptr,nullptr, basin_seq, rsg);
}